// Round 13
// baseline (233.963 us; speedup 1.0000x reference)
//
#include <hip/hip_runtime.h>
#include <math.h>

// Problem constants: B=4, S=1024, DIM=1280, H=16, HD=80
// Inputs fp32 (runtime-probed); OUTPUT FP32.
#define SCALE_F 0.11180339887498949f   // 80^-0.5
#define HDP 96                          // HD padded to multiple of 32 for QK^T

typedef short  short8  __attribute__((ext_vector_type(8)));
typedef short  short4v __attribute__((ext_vector_type(4)));
typedef float  f32x4   __attribute__((ext_vector_type(4)));
typedef __bf16 bf16x8  __attribute__((ext_vector_type(8)));
typedef __bf16 bf16x4  __attribute__((ext_vector_type(4)));

__device__ __forceinline__ float bf2f(short s) {
  union { unsigned u; float f; } v;
  v.u = ((unsigned)(unsigned short)s) << 16;
  return v.f;
}
__device__ __forceinline__ short f2b(float f) {
  __bf16 h = (__bf16)f;
  return __builtin_bit_cast(short, h);
}
__device__ __forceinline__ bool probe_is_bf16(const unsigned* probe) {
  return (probe[1] & 0xFFFFu) != 0u;
}
__device__ __forceinline__ float load_scalar(const void* p, int i, bool isb) {
  return isb ? bf2f(((const short*)p)[i]) : ((const float*)p)[i];
}

// async global->LDS, 16B per lane. HW LDS placement: wave-uniform base +
// lane*16 (m104/m108); per-lane pointer below coincides with that exactly.
__device__ __forceinline__ void gload_lds16(const short* g, short* l) {
  __builtin_amdgcn_global_load_lds(
      (const __attribute__((address_space(1))) void*)g,
      (__attribute__((address_space(3))) void*)l, 16, 0, 0);
}

template <typename V>
__device__ __forceinline__ auto mfma_try(V a, V b, f32x4 c, int)
    -> decltype(__builtin_amdgcn_mfma_f32_16x16x32_bf16(a, b, c, 0, 0, 0)) {
  return __builtin_amdgcn_mfma_f32_16x16x32_bf16(a, b, c, 0, 0, 0);
}
template <typename V>
__device__ __forceinline__ f32x4 mfma_try(V a, V b, f32x4 c, long) {
  return __builtin_amdgcn_mfma_f32_16x16x32_bf16(
      __builtin_bit_cast(bf16x8, a), __builtin_bit_cast(bf16x8, b), c, 0, 0, 0);
}
__device__ __forceinline__ f32x4 MFMA(short8 a, short8 b, f32x4 c) {
  return mfma_try(a, b, c, 0);
}

// 16x16x16 bf16 MFMA (k=16): A/B = 4 bf16 (2 VGPRs), C/D = f32x4.
// Builtin name varies across ROCm; 3-way guarded.
#if __has_builtin(__builtin_amdgcn_mfma_f32_16x16x16bf16_1k)
template <typename V>
__device__ __forceinline__ auto mfma16_try(V a, V b, f32x4 c, int)
    -> decltype(__builtin_amdgcn_mfma_f32_16x16x16bf16_1k(a, b, c, 0, 0, 0)) {
  return __builtin_amdgcn_mfma_f32_16x16x16bf16_1k(a, b, c, 0, 0, 0);
}
template <typename V>
__device__ __forceinline__ f32x4 mfma16_try(V a, V b, f32x4 c, long) {
  return __builtin_amdgcn_mfma_f32_16x16x16bf16_1k(
      __builtin_bit_cast(bf16x4, a), __builtin_bit_cast(bf16x4, b), c, 0, 0, 0);
}
__device__ __forceinline__ f32x4 MFMA16(short4v a, short4v b, f32x4 c) {
  return mfma16_try(a, b, c, 0);
}
#elif __has_builtin(__builtin_amdgcn_mfma_f32_16x16x16_bf16)
template <typename V>
__device__ __forceinline__ auto mfma16_try(V a, V b, f32x4 c, int)
    -> decltype(__builtin_amdgcn_mfma_f32_16x16x16_bf16(a, b, c, 0, 0, 0)) {
  return __builtin_amdgcn_mfma_f32_16x16x16_bf16(a, b, c, 0, 0, 0);
}
template <typename V>
__device__ __forceinline__ f32x4 mfma16_try(V a, V b, f32x4 c, long) {
  return __builtin_amdgcn_mfma_f32_16x16x16_bf16(
      __builtin_bit_cast(bf16x4, a), __builtin_bit_cast(bf16x4, b), c, 0, 0, 0);
}
__device__ __forceinline__ f32x4 MFMA16(short4v a, short4v b, f32x4 c) {
  return mfma16_try(a, b, c, 0);
}
#else
__device__ __forceinline__ f32x4 MFMA16(short4v a, short4v b, f32x4 c) {
  asm volatile("v_mfma_f32_16x16x16_bf16 %0, %1, %2, %0"
               : "+v"(c) : "v"(a), "v"(b));
  return c;
}
#endif

// ------------------------------------------------------- canonicalize: x->bf16
__global__ __launch_bounds__(256) void cvt_x_kernel(
    const void* __restrict__ xin, short* __restrict__ xout,
    const unsigned* __restrict__ probe) {
  bool isb = probe_is_bf16(probe);
  size_t i = ((size_t)blockIdx.x * 256 + threadIdx.x) * 8;
  if (isb) {
    *(short8*)&xout[i] = *(const short8*)((const short*)xin + i);
  } else {
    const float* f = (const float*)xin + i;
    float4 a0 = *(const float4*)f;
    float4 a1 = *(const float4*)(f + 4);
    short8 sv;
    sv[0] = f2b(a0.x); sv[1] = f2b(a0.y); sv[2] = f2b(a0.z); sv[3] = f2b(a0.w);
    sv[4] = f2b(a1.x); sv[5] = f2b(a1.y); sv[6] = f2b(a1.z); sv[7] = f2b(a1.w);
    *(short8*)&xout[i] = sv;
  }
}

// ---------------------------------------------------------------- transpose
__global__ __launch_bounds__(256) void transpose_kernel(
    const void* __restrict__ in, short* __restrict__ out, int R, int C,
    const unsigned* __restrict__ probe) {
  bool isb = probe_is_bf16(probe);
  __shared__ float tile[32][33];
  int t = threadIdx.x;
  int bx = blockIdx.x;  // over C
  int by = blockIdx.y;  // over R
  int r = t >> 3, c4 = (t & 7) * 4;
  size_t idx = (size_t)(by * 32 + r) * C + bx * 32 + c4;
  if (isb) {
    short4v v = *(const short4v*)((const short*)in + idx);
    tile[r][c4 + 0] = bf2f(v[0]);
    tile[r][c4 + 1] = bf2f(v[1]);
    tile[r][c4 + 2] = bf2f(v[2]);
    tile[r][c4 + 3] = bf2f(v[3]);
  } else {
    float4 v = *(const float4*)((const float*)in + idx);
    tile[r][c4 + 0] = v.x;
    tile[r][c4 + 1] = v.y;
    tile[r][c4 + 2] = v.z;
    tile[r][c4 + 3] = v.w;
  }
  __syncthreads();
  int rr = t >> 3, k4 = (t & 7) * 4;
  short4v o;
  o[0] = f2b(tile[k4 + 0][rr]);
  o[1] = f2b(tile[k4 + 1][rr]);
  o[2] = f2b(tile[k4 + 2][rr]);
  o[3] = f2b(tile[k4 + 3][rr]);
  *(short4v*)&out[(size_t)(bx * 32 + rr) * R + by * 32 + k4] = o;
}

// ---------------------------------------------------------------- QKV GEMM
// r13 = r11 exactly (best measured 49.4-50.4 µs). r12's XCD swizzle cut
// FETCH 83.5->51 MB but cost ~2.5 µs -- kernel is NOT BW-bound (T1
// regime-gate: swizzle pays only when HBM-bound); reverted.
__global__ __launch_bounds__(512, 2) void gemm_qkv_kernel(
    const short* __restrict__ X, const short* __restrict__ Wt,
    const void* __restrict__ bias, const unsigned* __restrict__ probe,
    short* __restrict__ Qw, short* __restrict__ Kw, short* __restrict__ Vt) {
  const int K = 1280;
  __shared__ short Al[2][2][8192];   // [slot][half][128*64]
  __shared__ short Bl[2][2][8192];
  int t = threadIdx.x;
  int bm = blockIdx.x / 15, bn = blockIdx.x % 15;
  int m0 = bm * 256, n0 = bn * 256;
  int w = t >> 6, lane = t & 63;
  int quad = lane >> 4, l16 = lane & 15, l8 = l16 & 7;
  int arow = (w >> 2) * 64 + l16;   // + mt*16 -> A row within half
  int brow = (w & 3) * 32 + l16;    // + nt*16 -> B row within half
  int sr = t >> 3, t8s = t * 8;
  int sjs = (t & 7) ^ (sr & 7);     // pre-swizzled global k-slot (involution)
  int soff0 = ((quad ^ l8) * 8);
  int soff1 = (((4 + quad) ^ l8) * 8);
  f32x4 acc[2][2][4][2] = {};       // [qm][qn][mt][nt], all-static indexing
  short8 afr[4][2];                 // A fragments of current (S,HA)
  short8 bf0[2][2], bf1[2][2];      // B fragments, half0 / half1 of current S

#define STAGE8(PTR, R0, KOFF, LP)                                            \
  {                                                                          \
    const short* g_ = (PTR) + (size_t)((R0) + sr) * 1280 + (KOFF) + sjs * 8; \
    gload_lds16(g_, (LP) + t8s);                                             \
    gload_lds16(g_ + 64 * 1280, (LP) + t8s + 4096);                          \
  }

#define READ_A(S, H)                                                         \
  {                                                                          \
    _Pragma("unroll") for (int mt = 0; mt < 4; mt++) {                       \
      int rp_ = (arow + mt * 16) * 64;                                       \
      afr[mt][0] = *(const short8*)&Al[S][H][rp_ + soff0];                   \
      afr[mt][1] = *(const short8*)&Al[S][H][rp_ + soff1];                   \
    }                                                                        \
  }
#define READ_B(DST, S, H)                                                    \
  {                                                                          \
    _Pragma("unroll") for (int nt = 0; nt < 2; nt++) {                       \
      int rp_ = (brow + nt * 16) * 64;                                       \
      DST[nt][0] = *(const short8*)&Bl[S][H][rp_ + soff0];                   \
      DST[nt][1] = *(const short8*)&Bl[S][H][rp_ + soff1];                   \
    }                                                                        \
  }
// one quadrant cluster (16 MFMA) with a counted lgkm wait before it
#define CLUST(QM, QN, BF, WAITI)                                             \
  {                                                                          \
    asm volatile("s_waitcnt lgkmcnt(" #WAITI ")" ::: "memory");              \
    __builtin_amdgcn_sched_barrier(0);                                       \
    _Pragma("unroll") for (int mt = 0; mt < 4; mt++)                         \
      _Pragma("unroll") for (int nt = 0; nt < 2; nt++) {                     \
        acc[QM][QN][mt][nt] = MFMA(afr[mt][0], BF[nt][0], acc[QM][QN][mt][nt]); \
        acc[QM][QN][mt][nt] = MFMA(afr[mt][1], BF[nt][1], acc[QM][QN][mt][nt]); \
      }                                                                      \
  }
#define BAR() __builtin_amdgcn_s_barrier()
#define VW4()                                                                \
  {                                                                          \
    asm volatile("s_waitcnt vmcnt(4)" ::: "memory");                         \
    __builtin_amdgcn_sched_barrier(0);                                       \
  }

  // prologue: tile0 (all 4 halves) + tile1 (A0,B0) = 12 loads/thread
  STAGE8(X,  m0,       0,  &Al[0][0][0]);
  STAGE8(X,  m0 + 128, 0,  &Al[0][1][0]);
  STAGE8(Wt, n0,       0,  &Bl[0][0][0]);
  STAGE8(Wt, n0 + 128, 0,  &Bl[0][1][0]);
  STAGE8(X,  m0,       64, &Al[1][0][0]);
  STAGE8(Wt, n0,       64, &Bl[1][0][0]);
  VW4();   // tile0's 8 loads landed
  BAR();

  for (int i = 0; i < 10; i++) {
    int k1 = (2 * i + 1) * 64;                       // <= 1216, always valid
    int k2 = (2 * i + 2) * 64; if (k2 >= K) k2 = 0;  // dummy (unread) on tail
    int k3 = (2 * i + 3) * 64; if (k3 >= K) k3 = 0;
    // ---- PhA (S=0): quadrants (0,0)+(0,1), 16 reads, 2 stage-pairs ----
    READ_A(0, 0); READ_B(bf0, 0, 0); READ_B(bf1, 0, 1);
    STAGE8(X,  m0 + 128, k1, &Al[1][1][0]);
    STAGE8(Wt, n0 + 128, k1, &Bl[1][1][0]);
    __builtin_amdgcn_s_setprio(1);
    CLUST(0, 0, bf0, 4);   // bf1's 4 reads land under this cluster
    CLUST(0, 1, bf1, 0);
    __builtin_amdgcn_s_setprio(0);
    BAR();
    // ---- PhB (S=0): quadrants (1,0)+(1,1), 8 reads ----
    READ_A(0, 1);
    STAGE8(X,  m0,       k2, &Al[0][0][0]);
    STAGE8(Wt, n0,       k2, &Bl[0][0][0]);
    __builtin_amdgcn_s_setprio(1);
    CLUST(1, 0, bf0, 0);
    CLUST(1, 1, bf1, 0);
    __builtin_amdgcn_s_setprio(0);
    VW4();                 // drains prevB + PhA stages -> slot1 ready
    BAR();
    // ---- PhA (S=1) ----
    READ_A(1, 0); READ_B(bf0, 1, 0); READ_B(bf1, 1, 1);
    STAGE8(X,  m0 + 128, k2, &Al[0][1][0]);
    STAGE8(Wt, n0 + 128, k2, &Bl[0][1][0]);
    __builtin_amdgcn_s_setprio(1);
    CLUST(0, 0, bf0, 4);
    CLUST(0, 1, bf1, 0);
    __builtin_amdgcn_s_setprio(0);
    BAR();
    // ---- PhB (S=1) ----
    READ_A(1, 1);
    STAGE8(X,  m0,       k3, &Al[1][0][0]);
    STAGE8(Wt, n0,       k3, &Bl[1][0][0]);
    __builtin_amdgcn_s_setprio(1);
    CLUST(1, 0, bf0, 0);
    CLUST(1, 1, bf1, 0);
    __builtin_amdgcn_s_setprio(0);
    VW4();                 // drains PhB(S=0) + PhA(S=1) stages -> slot0 ready
    BAR();
  }
  asm volatile("s_waitcnt vmcnt(0)" ::: "memory");   // drain dummy stages
  __builtin_amdgcn_sched_barrier(0);

  bool isb = probe_is_bf16(probe);
  float bv[2][2];
#pragma unroll
  for (int qn = 0; qn < 2; qn++)
#pragma unroll
    for (int nt = 0; nt < 2; nt++)
      bv[qn][nt] =
          load_scalar(bias, n0 + qn * 128 + (w & 3) * 32 + nt * 16 + l16, isb);
#pragma unroll
  for (int qm = 0; qm < 2; qm++)
#pragma unroll
    for (int mt = 0; mt < 4; mt++) {
      int mbase = m0 + qm * 128 + (w >> 2) * 64 + mt * 16 + quad * 4;
      int b = mbase >> 10, sbase = mbase & 1023;
#pragma unroll
      for (int qn = 0; qn < 2; qn++)
#pragma unroll
        for (int nt = 0; nt < 2; nt++) {
          int n = n0 + qn * 128 + (w & 3) * 32 + nt * 16 + l16;
          int which = n / 1280;
          int rmod = n - which * 1280;
          int h = rmod / 80;
          int d = rmod - h * 80;
          int bh = b * 16 + h;
          if (which == 2) {
            short4v vv;
#pragma unroll
            for (int reg = 0; reg < 4; reg++)
              vv[reg] = f2b(acc[qm][qn][mt][nt][reg] + bv[qn][nt]);
            *(short4v*)&Vt[((size_t)bh * 80 + d) * 1024 + sbase] = vv;
          } else {
            short* dst = (which == 0 ? Qw : Kw);
#pragma unroll
            for (int reg = 0; reg < 4; reg++)
              dst[((size_t)bh * 1024 + sbase + reg) * HDP + d] =
                  f2b(acc[qm][qn][mt][nt][reg] + bv[qn][nt]);
          }
        }
    }
#undef STAGE8
#undef READ_A
#undef READ_B
#undef CLUST
#undef BAR
#undef VW4
}

// ---------------------------------------------------------------- RoPE
// r10 (verified): vectorized; each thread owns chunk pair (p*8, 40+p*8).
__global__ __launch_bounds__(256) void rope_kernel(
    short* __restrict__ Qw, short* __restrict__ Kw,
    const void* __restrict__ cosb, const void* __restrict__ sinb,
    const unsigned* __restrict__ probe) {
  bool isb = probe_is_bf16(probe);
  int tg = blockIdx.x * 256 + threadIdx.x;   // 0..655359
  int row_all = tg / 5;                      // 0..131071
  int p = tg - row_all * 5;                  // 0..4
  int which = row_all >> 16;                 // 0 = Q, 1 = K
  int r = row_all & 65535;                   // bh*1024 + s
  int s = r & 1023;
  short* ptr = (which ? Kw : Qw) + (size_t)r * HDP;
  float scale = which ? 1.0f : SCALE_F;
  int d0 = p * 8, d1 = 40 + p * 8;
  short8 a = *(const short8*)&ptr[d0];
  short8 b = *(const short8*)&ptr[d1];
  float c0[8], s0[8], c1[8], s1[8];
  if (isb) {
    const short* cb = (const short*)cosb + s * 80;
    const short* sb = (const short*)sinb + s * 80;
    short8 vc0 = *(const short8*)&cb[d0];
    short8 vs0 = *(const short8*)&sb[d0];
    short8 vc1 = *(const short8*)&cb[d1];
    short8 vs1 = *(const short8*)&sb[d1];
#pragma unroll
    for (int j = 0; j < 8; j++) {
      c0[j] = bf2f(vc0[j]); s0[j] = bf2f(vs0[j]);
      c1[j] = bf2f(vc1[j]); s1[j] = bf2f(vs1[j]);
    }
  } else {
    const float* cb = (const float*)cosb + s * 80;
    const float* sb = (const float*)sinb + s * 80;
    float4 vc0a = *(const float4*)&cb[d0];
    float4 vc0b = *(const float4*)&cb[d0 + 4];
    float4 vs0a = *(const float4*)&sb[d0];
    float4 vs0b = *(const float4*)&sb[d0 + 4];
    float4 vc1a = *(const float4*)&cb[d1];
    float4 vc1b = *(const float4*)&cb[d1 + 4];
    float4 vs1a = *(const float4*)&sb[d1];
    float4 vs1b = *(const float4*)&sb[d1 + 4];
    c0[0] = vc0a.x; c0[1] = vc0a.y; c0[2] = vc0a.z; c0[3] = vc0a.w;
    c0[4] = vc0b.x; c0[5] = vc0b.y; c0[6] = vc0b.z; c0[7] = vc0b.w;
    s0[0] = vs0a.x; s0[1] = vs0a.y; s0[2] = vs0a.z; s0[3] = vs0a.w;
    s0[4] = vs0b.x; s0[5] = vs0b.y; s0[6] = vs0b.z; s0[7] = vs0b.w;
    c1[0] = vc1a.x; c1[1] = vc1a.y; c1[2] = vc1a.z; c1[3] = vc1a.w;
    c1[4] = vc1b.x; c1[5] = vc1b.y; c1[6] = vc1b.z; c1[7] = vc1b.w;
    s1[0] = vs1a.x; s1[1] = vs1a.y; s1[2] = vs1a.z; s1[3] = vs1a.w;
    s1[4] = vs1b.x; s1[5] = vs1b.y; s1[6] = vs1b.z; s1[7] = vs1b.w;
  }
  short8 o0, o1;
#pragma unroll
  for (int j = 0; j < 8; j++) {
    float av = bf2f(a[j]), bv = bf2f(b[j]);
    o0[j] = f2b((av * c0[j] - bv * s0[j]) * scale);
    o1[j] = f2b((bv * c1[j] + av * s1[j]) * scale);
  }
  *(short8*)&ptr[d0] = o0;
  *(short8*)&ptr[d1] = o1;
  if (p == 0) {
    short8 z = {};
    *(short8*)&ptr[80] = z;
    *(short8*)&ptr[88] = z;
  }
}

// ---------------------------------------------------------------- attention
// r13 = r9 + T5 setprio around MFMA clusters (attn is the structure where
// T5 measured +4-7%: multi-block/CU, waves at independent phases -- m191).
__global__ __launch_bounds__(512, 4) void attn_kernel(
    const short* __restrict__ Qw, const short* __restrict__ Kw,
    const short* __restrict__ Vt, short* __restrict__ out) {
  __shared__ short Klds[2][64 * 104];
  __shared__ short Vlds[2][80 * 72];
  int t = threadIdx.x;
  int w = t >> 6, lane = t & 63;
  int quad = lane >> 4, l16 = lane & 15;
  int bh = blockIdx.x & 63;        // XCD swizzle: same bh -> same XCD
  int qt = blockIdx.x >> 6;        // 0..7
  int q0 = qt * 128;
  const short* Kb = Kw + (size_t)bh * 1024 * HDP;
  const short* Vb = Vt + (size_t)bh * 80 * 1024;

  short8 aq[3];
  {
    const short* qrow = Qw + ((size_t)bh * 1024 + q0 + w * 16 + l16) * HDP;
#pragma unroll
    for (int ks = 0; ks < 3; ks++)
      aq[ks] = *(const short8*)&qrow[ks * 32 + quad * 8];
  }

  short8 kreg[2], vreg[2];
#define PREFETCH(c)                                                        \
  {                                                                        \
    {                                                                      \
      int row = t / 12, col = (t % 12) * 8;                                \
      kreg[0] = *(const short8*)&Kb[(size_t)((c) + row) * HDP + col];      \
    }                                                                      \
    if (t < 256) {                                                         \
      int idx = 512 + t;                                                   \
      int row = idx / 12, col = (idx % 12) * 8;                            \
      kreg[1] = *(const short8*)&Kb[(size_t)((c) + row) * HDP + col];      \
    }                                                                      \
    {                                                                      \
      int d = t >> 3, s0 = (t & 7) * 8;                                    \
      vreg[0] = *(const short8*)&Vb[(size_t)d * 1024 + (c) + s0];          \
    }                                                                      \
    if (t < 128) {                                                         \
      int idx = 512 + t;                                                   \
      int d = idx >> 3, s0 = (idx & 7) * 8;                                \
      vreg[1] = *(const short8*)&Vb[(size_t)d * 1024 + (c) + s0];          \
    }                                                                      \
  }
#define STORE_LDS(P)                                                       \
  {                                                                        \
    {                                                                      \
      int row = t / 12, col = (t % 12) * 8;                                \
      *(short8*)&Klds[P][row * 104 + col] = kreg[0];                       \
    }                                                                      \
    if (t < 256) {                                                         \
      int idx = 512 + t;                                                   \
      int row = idx / 12, col = (idx % 12) * 8;                            \
      *(short8*)&Klds[P][row * 104 + col] = kreg[1];                       \
    }                                                                      \
    {                                                                      \
      int d = t >> 3, s0 = (t & 7) * 8;                                    \
      *(short8*)&Vlds[P][d * 72 + s0] = vreg[0];                           \
    }                                                                      \
    if (t < 128) {                                                         \
      int idx = 512 + t;                                                   \
      int d = idx >> 3, s0 = (idx & 7) * 8;                                \
      *(short8*)&Vlds[P][d * 72 + s0] = vreg[1];                           \
    }                                                                      \
  }

  PREFETCH(0);
  STORE_LDS(0);
  __syncthreads();

  f32x4 ofr[5] = {};
  float lsum = 0.f;

  int p = 0;
  for (int c = 0; c < 1024; c += 64, p ^= 1) {
    if (c + 64 < 1024) PREFETCH(c + 64);   // global loads fly under compute
    const short* Kl = &Klds[p][0];
    const short* Vl = &Vlds[p][0];
    f32x4 sf[4] = {};
    __builtin_amdgcn_s_setprio(1);
#pragma unroll
    for (int nt = 0; nt < 4; nt++) {
      short8 bk0 = *(const short8*)&Kl[(nt * 16 + l16) * 104 + 0 * 32 + quad * 8];
      short8 bk1 = *(const short8*)&Kl[(nt * 16 + l16) * 104 + 1 * 32 + quad * 8];
      short8 bk2 = *(const short8*)&Kl[(nt * 16 + l16) * 104 + 2 * 32 + quad * 8];
      sf[nt] = MFMA(bk0, aq[0], sf[nt]);   // A=K (rows kv), B=Q (cols q)
      sf[nt] = MFMA(bk1, aq[1], sf[nt]);
      sf[nt] = MFMA(bk2, aq[2], sf[nt]);
    }
    __builtin_amdgcn_s_setprio(0);
    short4v bp[4];
#pragma unroll
    for (int nt = 0; nt < 4; nt++) {
      float e0 = __expf(fminf(sf[nt][0], 30.f));
      float e1 = __expf(fminf(sf[nt][1], 30.f));
      float e2 = __expf(fminf(sf[nt][2], 30.f));
      float e3 = __expf(fminf(sf[nt][3], 30.f));
      lsum += (e0 + e1) + (e2 + e3);
      bp[nt][0] = f2b(e0); bp[nt][1] = f2b(e1);
      bp[nt][2] = f2b(e2); bp[nt][3] = f2b(e3);
    }
    __builtin_amdgcn_s_setprio(1);
#pragma unroll
    for (int cc = 0; cc < 4; cc++)
#pragma unroll
      for (int nt5 = 0; nt5 < 5; nt5++) {
        short4v va =
            *(const short4v*)&Vl[(nt5 * 16 + l16) * 72 + cc * 16 + quad * 4];
        ofr[nt5] = MFMA16(va, bp[cc], ofr[nt5]);
      }
    __builtin_amdgcn_s_setprio(0);
    if (c + 64 < 1024) {
      STORE_LDS(p ^ 1);       // idle buffer; readers of it passed last barrier
      __syncthreads();        // publish + close this iter's reads of buf p
    }
  }
  lsum += __shfl_xor(lsum, 16);
  lsum += __shfl_xor(lsum, 32);
  float inv = 1.f / lsum;
  int b = bh >> 4, h = bh & 15;
  int s = q0 + w * 16 + l16;
#pragma unroll
  for (int nt5 = 0; nt5 < 5; nt5++) {
    short4v o;
#pragma unroll
    for (int j = 0; j < 4; j++) o[j] = f2b(ofr[nt5][j] * inv);
    *(short4v*)&out[((size_t)(b * 1024 + s)) * 1280 + h * 80 + nt5 * 16 +
                    quad * 4] = o;
  }
}

// ---------------------------------------------------------------- proj GEMM
__global__ __launch_bounds__(256) void gemm_proj_kernel(
    const short* __restrict__ A, const short* __restrict__ Wt,
    const void* __restrict__ bias, const unsigned* __restrict__ probe,
    float* __restrict__ out) {
  const int K = 1280;
  __shared__ short As[2][128 * 32];
  __shared__ short Bs[2][128 * 32];
  int t = threadIdx.x;
  int bm = blockIdx.x / 10;
  int bn = blockIdx.x % 10;
  int m0 = bm * 128, n0 = bn * 128;
  int w = t >> 6, lane = t & 63;
  int wm = w & 1, wn = w >> 1;
  int quad = lane >> 4, l16 = lane & 15;
  int row = t >> 2, ch = (t & 3) * 8, row2 = row + 64;
  int t8 = t * 8;
  const short* Ar  = A  + (size_t)(m0 + row)  * K + ch;
  const short* Ar2 = A  + (size_t)(m0 + row2) * K + ch;
  const short* Wr  = Wt + (size_t)(n0 + row)  * K + ch;
  const short* Wr2 = Wt + (size_t)(n0 + row2) * K + ch;
  f32x4 acc[4][4] = {};
  gload_lds16(Ar,  &As[0][t8]);
  gload_lds16(Ar2, &As[0][t8 + 2048]);
  gload_lds16(Wr,  &Bs[0][t8]);
  gload_lds16(Wr2, &Bs[0][t8 + 2048]);
  __syncthreads();
  int p = 0;
#define PROJ_COMPUTE(pp)                                                      \
  {                                                                           \
    short8 af[4], bfr[4];                                                     \
    _Pragma("unroll") for (int mt = 0; mt < 4; mt++)                          \
        af[mt] = *(const short8*)&As[pp][(wm * 64 + mt * 16 + l16) * 32 + quad * 8]; \
    _Pragma("unroll") for (int nt = 0; nt < 4; nt++)                          \
        bfr[nt] = *(const short8*)&Bs[pp][(wn * 64 + nt * 16 + l16) * 32 + quad * 8]; \
    _Pragma("unroll") for (int mt = 0; mt < 4; mt++)                          \
        _Pragma("unroll") for (int nt = 0; nt < 4; nt++)                      \
            acc[mt][nt] = MFMA(af[mt], bfr[nt], acc[mt][nt]);                 \
  }
  for (int k0 = 32; k0 < K; k0 += 32, p ^= 1) {
    gload_lds16(Ar + k0,  &As[p ^ 1][t8]);
    gload_lds16(Ar2 + k0, &As[p ^ 1][t8 + 2048]);
    gload_lds16(Wr + k0,  &Bs[p ^ 1][t8]);
    gload_lds16(Wr2 + k0, &Bs[p ^ 1][t8 + 2048]);
    PROJ_COMPUTE(p);
    __syncthreads();
  }
  PROJ_COMPUTE(p);
  bool isb = probe_is_bf16(probe);
  float bv[4];
#pragma unroll
  for (int nt = 0; nt < 4; nt++)
    bv[nt] = load_scalar(bias, n0 + wn * 64 + nt * 16 + l16, isb);
#pragma unroll
  for (int mt = 0; mt < 4; mt++) {
#pragma unroll
    for (int nt = 0; nt < 4; nt++) {
      int n = n0 + wn * 64 + nt * 16 + l16;
#pragma unroll
      for (int reg = 0; reg < 4; reg++) {
        int m = m0 + wm * 64 + mt * 16 + quad * 4 + reg;
        out[(size_t)m * 1280 + n] = acc[mt][nt][reg] + bv[nt];  // FP32 store
      }
    }
  }
}

extern "C" void kernel_launch(void* const* d_in, const int* in_sizes, int n_in,
                              void* d_out, int out_size, void* d_ws, size_t ws_size,
                              hipStream_t stream) {
  const void* x        = d_in[0];
  const void* rope_cos = d_in[1];
  const void* rope_sin = d_in[2];
  const void* Wqkv     = d_in[3];
  const void* bqkv     = d_in[4];
  const void* Wproj    = d_in[5];
  const void* bproj    = d_in[6];
  const unsigned* probe = (const unsigned*)rope_cos;
  char* ws = (char*)d_ws;
  short* Wt1 = (short*)(ws + 0);          // 1280*3840*2 = 9,830,400
  short* Wt2 = (short*)(ws + 9830400);    // 1280*1280*2 = 3,276,800
  short* Qw  = (short*)(ws + 13107200);   // 64*1024*96*2 = 12,582,912
  short* Kw  = (short*)(ws + 25690112);   // 12,582,912
  short* Vt  = (short*)(ws + 38273024);   // 64*1024*80*2 = 10,485,760
  short* Xb  = (short*)(ws + 48758784);   // 4096*1280*2 = 10,485,760
  short* At  = (short*)(ws + 48758784);   // aliases Xb (disjoint lifetimes)

  cvt_x_kernel<<<2560, 256, 0, stream>>>(x, Xb, probe);
  transpose_kernel<<<dim3(3840 / 32, 1280 / 32), 256, 0, stream>>>(Wqkv, Wt1, 1280, 3840, probe);
  transpose_kernel<<<dim3(1280 / 32, 1280 / 32), 256, 0, stream>>>(Wproj, Wt2, 1280, 1280, probe);
  gemm_qkv_kernel<<<240, 512, 0, stream>>>(Xb, Wt1, bqkv, probe, Qw, Kw, Vt);
  rope_kernel<<<2560, 256, 0, stream>>>(Qw, Kw, rope_cos, rope_sin, probe);
  attn_kernel<<<512, 512, 0, stream>>>(Qw, Kw, Vt, At);
  gemm_proj_kernel<<<32 * 10, 256, 0, stream>>>(At, Wt2, bproj, probe, (float*)d_out);
}

// Round 15
// 232.534 us; speedup vs baseline: 1.0061x; 1.0061x over previous
//
#include <hip/hip_runtime.h>
#include <math.h>

// Problem constants: B=4, S=1024, DIM=1280, H=16, HD=80
// Inputs fp32 (runtime-probed); OUTPUT FP32.
#define SCALE_F 0.11180339887498949f   // 80^-0.5
#define HDP 96                          // HD padded to multiple of 32 for QK^T

typedef short  short8  __attribute__((ext_vector_type(8)));
typedef short  short4v __attribute__((ext_vector_type(4)));
typedef float  f32x4   __attribute__((ext_vector_type(4)));
typedef __bf16 bf16x8  __attribute__((ext_vector_type(8)));
typedef __bf16 bf16x4  __attribute__((ext_vector_type(4)));

__device__ __forceinline__ float bf2f(short s) {
  union { unsigned u; float f; } v;
  v.u = ((unsigned)(unsigned short)s) << 16;
  return v.f;
}
__device__ __forceinline__ short f2b(float f) {
  __bf16 h = (__bf16)f;
  return __builtin_bit_cast(short, h);
}
__device__ __forceinline__ bool probe_is_bf16(const unsigned* probe) {
  return (probe[1] & 0xFFFFu) != 0u;
}
__device__ __forceinline__ float load_scalar(const void* p, int i, bool isb) {
  return isb ? bf2f(((const short*)p)[i]) : ((const float*)p)[i];
}

// async global->LDS, 16B per lane. HW LDS placement: wave-uniform base +
// lane*16 (m104/m108); per-lane pointer below coincides with that exactly.
__device__ __forceinline__ void gload_lds16(const short* g, short* l) {
  __builtin_amdgcn_global_load_lds(
      (const __attribute__((address_space(1))) void*)g,
      (__attribute__((address_space(3))) void*)l, 16, 0, 0);
}

template <typename V>
__device__ __forceinline__ auto mfma_try(V a, V b, f32x4 c, int)
    -> decltype(__builtin_amdgcn_mfma_f32_16x16x32_bf16(a, b, c, 0, 0, 0)) {
  return __builtin_amdgcn_mfma_f32_16x16x32_bf16(a, b, c, 0, 0, 0);
}
template <typename V>
__device__ __forceinline__ f32x4 mfma_try(V a, V b, f32x4 c, long) {
  return __builtin_amdgcn_mfma_f32_16x16x32_bf16(
      __builtin_bit_cast(bf16x8, a), __builtin_bit_cast(bf16x8, b), c, 0, 0, 0);
}
__device__ __forceinline__ f32x4 MFMA(short8 a, short8 b, f32x4 c) {
  return mfma_try(a, b, c, 0);
}

// 16x16x16 bf16 MFMA (k=16): A/B = 4 bf16 (2 VGPRs), C/D = f32x4.
// Builtin name varies across ROCm; 3-way guarded.
#if __has_builtin(__builtin_amdgcn_mfma_f32_16x16x16bf16_1k)
template <typename V>
__device__ __forceinline__ auto mfma16_try(V a, V b, f32x4 c, int)
    -> decltype(__builtin_amdgcn_mfma_f32_16x16x16bf16_1k(a, b, c, 0, 0, 0)) {
  return __builtin_amdgcn_mfma_f32_16x16x16bf16_1k(a, b, c, 0, 0, 0);
}
template <typename V>
__device__ __forceinline__ f32x4 mfma16_try(V a, V b, f32x4 c, long) {
  return __builtin_amdgcn_mfma_f32_16x16x16bf16_1k(
      __builtin_bit_cast(bf16x4, a), __builtin_bit_cast(bf16x4, b), c, 0, 0, 0);
}
__device__ __forceinline__ f32x4 MFMA16(short4v a, short4v b, f32x4 c) {
  return mfma16_try(a, b, c, 0);
}
#elif __has_builtin(__builtin_amdgcn_mfma_f32_16x16x16_bf16)
template <typename V>
__device__ __forceinline__ auto mfma16_try(V a, V b, f32x4 c, int)
    -> decltype(__builtin_amdgcn_mfma_f32_16x16x16_bf16(a, b, c, 0, 0, 0)) {
  return __builtin_amdgcn_mfma_f32_16x16x16_bf16(a, b, c, 0, 0, 0);
}
template <typename V>
__device__ __forceinline__ f32x4 mfma16_try(V a, V b, f32x4 c, long) {
  return __builtin_amdgcn_mfma_f32_16x16x16_bf16(
      __builtin_bit_cast(bf16x4, a), __builtin_bit_cast(bf16x4, b), c, 0, 0, 0);
}
__device__ __forceinline__ f32x4 MFMA16(short4v a, short4v b, f32x4 c) {
  return mfma16_try(a, b, c, 0);
}
#else
__device__ __forceinline__ f32x4 MFMA16(short4v a, short4v b, f32x4 c) {
  asm volatile("v_mfma_f32_16x16x16_bf16 %0, %1, %2, %0"
               : "+v"(c) : "v"(a), "v"(b));
  return c;
}
#endif

// ------------------------------------------------ fused preprocessing
// r15: one launch replaces {cvt_x, transpose(Wqkv), transpose(Wproj)}.
// ALWAYS runs the cvt section (ncvt fixed at 2560); dtype dispatch is
// device-side via probe, identical semantics to the verified r13 path.
// (r14's host-side in_sizes dtype inference caused NaN -- in_sizes
// semantics unproven; removed.)
__global__ __launch_bounds__(256) void preproc_kernel(
    const void* __restrict__ xin, short* __restrict__ xout,
    const void* __restrict__ wqkv, short* __restrict__ wt1,
    const void* __restrict__ wproj, short* __restrict__ wt2,
    const unsigned* __restrict__ probe) {
  __shared__ float tile[32][33];
  bool isb = probe_is_bf16(probe);
  int bid = blockIdx.x;
  int t = threadIdx.x;
  if (bid < 2560) {  // ---- cvt_x: fp32 -> bf16 (or copy) ----
    size_t i = ((size_t)bid * 256 + t) * 8;
    if (isb) {
      *(short8*)&xout[i] = *(const short8*)((const short*)xin + i);
    } else {
      const float* f = (const float*)xin + i;
      float4 a0 = *(const float4*)f;
      float4 a1 = *(const float4*)(f + 4);
      short8 sv;
      sv[0] = f2b(a0.x); sv[1] = f2b(a0.y); sv[2] = f2b(a0.z); sv[3] = f2b(a0.w);
      sv[4] = f2b(a1.x); sv[5] = f2b(a1.y); sv[6] = f2b(a1.z); sv[7] = f2b(a1.w);
      *(short8*)&xout[i] = sv;
    }
    return;
  }
  // ---- weight transposes ----
  int b2 = bid - 2560;
  const void* in; short* out; int R, C, bx, by;
  if (b2 < 4800) {
    in = wqkv; out = wt1; R = 1280; C = 3840;
    bx = b2 % 120; by = b2 / 120;
  } else {
    int b3 = b2 - 4800;
    in = wproj; out = wt2; R = 1280; C = 1280;
    bx = b3 % 40; by = b3 / 40;
  }
  int r = t >> 3, c4 = (t & 7) * 4;
  size_t idx = (size_t)(by * 32 + r) * C + bx * 32 + c4;
  if (isb) {
    short4v v = *(const short4v*)((const short*)in + idx);
    tile[r][c4 + 0] = bf2f(v[0]);
    tile[r][c4 + 1] = bf2f(v[1]);
    tile[r][c4 + 2] = bf2f(v[2]);
    tile[r][c4 + 3] = bf2f(v[3]);
  } else {
    float4 v = *(const float4*)((const float*)in + idx);
    tile[r][c4 + 0] = v.x;
    tile[r][c4 + 1] = v.y;
    tile[r][c4 + 2] = v.z;
    tile[r][c4 + 3] = v.w;
  }
  __syncthreads();
  int rr = t >> 3, k4 = (t & 7) * 4;
  short4v o;
  o[0] = f2b(tile[k4 + 0][rr]);
  o[1] = f2b(tile[k4 + 1][rr]);
  o[2] = f2b(tile[k4 + 2][rr]);
  o[3] = f2b(tile[k4 + 3][rr]);
  *(short4v*)&out[(size_t)(bx * 32 + rr) * R + by * 32 + k4] = o;
}

// ---------------------------------------------------------------- QKV GEMM
// r11 structure (best measured 49.4-50.4 µs): 256x256, BK=64, 8 waves,
// 4 merged phases / 2 K-tiles, T2 swizzle (0 conflicts), counted vmcnt,
// register-hoisted fragments. r12's XCD swizzle reverted (not BW-bound).
__global__ __launch_bounds__(512, 2) void gemm_qkv_kernel(
    const short* __restrict__ X, const short* __restrict__ Wt,
    const void* __restrict__ bias, const unsigned* __restrict__ probe,
    short* __restrict__ Qw, short* __restrict__ Kw, short* __restrict__ Vt) {
  const int K = 1280;
  __shared__ short Al[2][2][8192];   // [slot][half][128*64]
  __shared__ short Bl[2][2][8192];
  int t = threadIdx.x;
  int bm = blockIdx.x / 15, bn = blockIdx.x % 15;
  int m0 = bm * 256, n0 = bn * 256;
  int w = t >> 6, lane = t & 63;
  int quad = lane >> 4, l16 = lane & 15, l8 = l16 & 7;
  int arow = (w >> 2) * 64 + l16;   // + mt*16 -> A row within half
  int brow = (w & 3) * 32 + l16;    // + nt*16 -> B row within half
  int sr = t >> 3, t8s = t * 8;
  int sjs = (t & 7) ^ (sr & 7);     // pre-swizzled global k-slot (involution)
  int soff0 = ((quad ^ l8) * 8);
  int soff1 = (((4 + quad) ^ l8) * 8);
  f32x4 acc[2][2][4][2] = {};       // [qm][qn][mt][nt], all-static indexing
  short8 afr[4][2];                 // A fragments of current (S,HA)
  short8 bf0[2][2], bf1[2][2];      // B fragments, half0 / half1 of current S

#define STAGE8(PTR, R0, KOFF, LP)                                            \
  {                                                                          \
    const short* g_ = (PTR) + (size_t)((R0) + sr) * 1280 + (KOFF) + sjs * 8; \
    gload_lds16(g_, (LP) + t8s);                                             \
    gload_lds16(g_ + 64 * 1280, (LP) + t8s + 4096);                          \
  }

#define READ_A(S, H)                                                         \
  {                                                                          \
    _Pragma("unroll") for (int mt = 0; mt < 4; mt++) {                       \
      int rp_ = (arow + mt * 16) * 64;                                       \
      afr[mt][0] = *(const short8*)&Al[S][H][rp_ + soff0];                   \
      afr[mt][1] = *(const short8*)&Al[S][H][rp_ + soff1];                   \
    }                                                                        \
  }
#define READ_B(DST, S, H)                                                    \
  {                                                                          \
    _Pragma("unroll") for (int nt = 0; nt < 2; nt++) {                       \
      int rp_ = (brow + nt * 16) * 64;                                       \
      DST[nt][0] = *(const short8*)&Bl[S][H][rp_ + soff0];                   \
      DST[nt][1] = *(const short8*)&Bl[S][H][rp_ + soff1];                   \
    }                                                                        \
  }
// one quadrant cluster (16 MFMA) with a counted lgkm wait before it
#define CLUST(QM, QN, BF, WAITI)                                             \
  {                                                                          \
    asm volatile("s_waitcnt lgkmcnt(" #WAITI ")" ::: "memory");              \
    __builtin_amdgcn_sched_barrier(0);                                       \
    _Pragma("unroll") for (int mt = 0; mt < 4; mt++)                         \
      _Pragma("unroll") for (int nt = 0; nt < 2; nt++) {                     \
        acc[QM][QN][mt][nt] = MFMA(afr[mt][0], BF[nt][0], acc[QM][QN][mt][nt]); \
        acc[QM][QN][mt][nt] = MFMA(afr[mt][1], BF[nt][1], acc[QM][QN][mt][nt]); \
      }                                                                      \
  }
#define BAR() __builtin_amdgcn_s_barrier()
#define VW4()                                                                \
  {                                                                          \
    asm volatile("s_waitcnt vmcnt(4)" ::: "memory");                         \
    __builtin_amdgcn_sched_barrier(0);                                       \
  }

  // prologue: tile0 (all 4 halves) + tile1 (A0,B0) = 12 loads/thread
  STAGE8(X,  m0,       0,  &Al[0][0][0]);
  STAGE8(X,  m0 + 128, 0,  &Al[0][1][0]);
  STAGE8(Wt, n0,       0,  &Bl[0][0][0]);
  STAGE8(Wt, n0 + 128, 0,  &Bl[0][1][0]);
  STAGE8(X,  m0,       64, &Al[1][0][0]);
  STAGE8(Wt, n0,       64, &Bl[1][0][0]);
  VW4();   // tile0's 8 loads landed
  BAR();

  for (int i = 0; i < 10; i++) {
    int k1 = (2 * i + 1) * 64;                       // <= 1216, always valid
    int k2 = (2 * i + 2) * 64; if (k2 >= K) k2 = 0;  // dummy (unread) on tail
    int k3 = (2 * i + 3) * 64; if (k3 >= K) k3 = 0;
    // ---- PhA (S=0): quadrants (0,0)+(0,1), 16 reads, 2 stage-pairs ----
    READ_A(0, 0); READ_B(bf0, 0, 0); READ_B(bf1, 0, 1);
    STAGE8(X,  m0 + 128, k1, &Al[1][1][0]);
    STAGE8(Wt, n0 + 128, k1, &Bl[1][1][0]);
    __builtin_amdgcn_s_setprio(1);
    CLUST(0, 0, bf0, 4);   // bf1's 4 reads land under this cluster
    CLUST(0, 1, bf1, 0);
    __builtin_amdgcn_s_setprio(0);
    BAR();
    // ---- PhB (S=0): quadrants (1,0)+(1,1), 8 reads ----
    READ_A(0, 1);
    STAGE8(X,  m0,       k2, &Al[0][0][0]);
    STAGE8(Wt, n0,       k2, &Bl[0][0][0]);
    __builtin_amdgcn_s_setprio(1);
    CLUST(1, 0, bf0, 0);
    CLUST(1, 1, bf1, 0);
    __builtin_amdgcn_s_setprio(0);
    VW4();                 // drains prevB + PhA stages -> slot1 ready
    BAR();
    // ---- PhA (S=1) ----
    READ_A(1, 0); READ_B(bf0, 1, 0); READ_B(bf1, 1, 1);
    STAGE8(X,  m0 + 128, k2, &Al[0][1][0]);
    STAGE8(Wt, n0 + 128, k2, &Bl[0][1][0]);
    __builtin_amdgcn_s_setprio(1);
    CLUST(0, 0, bf0, 4);
    CLUST(0, 1, bf1, 0);
    __builtin_amdgcn_s_setprio(0);
    BAR();
    // ---- PhB (S=1) ----
    READ_A(1, 1);
    STAGE8(X,  m0,       k3, &Al[1][0][0]);
    STAGE8(Wt, n0,       k3, &Bl[1][0][0]);
    __builtin_amdgcn_s_setprio(1);
    CLUST(1, 0, bf0, 0);
    CLUST(1, 1, bf1, 0);
    __builtin_amdgcn_s_setprio(0);
    VW4();                 // drains PhB(S=0) + PhA(S=1) stages -> slot0 ready
    BAR();
  }
  asm volatile("s_waitcnt vmcnt(0)" ::: "memory");   // drain dummy stages
  __builtin_amdgcn_sched_barrier(0);

  bool isb = probe_is_bf16(probe);
  float bv[2][2];
#pragma unroll
  for (int qn = 0; qn < 2; qn++)
#pragma unroll
    for (int nt = 0; nt < 2; nt++)
      bv[qn][nt] =
          load_scalar(bias, n0 + qn * 128 + (w & 3) * 32 + nt * 16 + l16, isb);
#pragma unroll
  for (int qm = 0; qm < 2; qm++)
#pragma unroll
    for (int mt = 0; mt < 4; mt++) {
      int mbase = m0 + qm * 128 + (w >> 2) * 64 + mt * 16 + quad * 4;
      int b = mbase >> 10, sbase = mbase & 1023;
#pragma unroll
      for (int qn = 0; qn < 2; qn++)
#pragma unroll
        for (int nt = 0; nt < 2; nt++) {
          int n = n0 + qn * 128 + (w & 3) * 32 + nt * 16 + l16;
          int which = n / 1280;
          int rmod = n - which * 1280;
          int h = rmod / 80;
          int d = rmod - h * 80;
          int bh = b * 16 + h;
          if (which == 2) {
            short4v vv;
#pragma unroll
            for (int reg = 0; reg < 4; reg++)
              vv[reg] = f2b(acc[qm][qn][mt][nt][reg] + bv[qn][nt]);
            *(short4v*)&Vt[((size_t)bh * 80 + d) * 1024 + sbase] = vv;
          } else {
            short* dst = (which == 0 ? Qw : Kw);
#pragma unroll
            for (int reg = 0; reg < 4; reg++)
              dst[((size_t)bh * 1024 + sbase + reg) * HDP + d] =
                  f2b(acc[qm][qn][mt][nt][reg] + bv[qn][nt]);
          }
        }
    }
#undef STAGE8
#undef READ_A
#undef READ_B
#undef CLUST
#undef BAR
#undef VW4
}

// ---------------------------------------------------------------- RoPE
// r10 (verified): vectorized; each thread owns chunk pair (p*8, 40+p*8).
__global__ __launch_bounds__(256) void rope_kernel(
    short* __restrict__ Qw, short* __restrict__ Kw,
    const void* __restrict__ cosb, const void* __restrict__ sinb,
    const unsigned* __restrict__ probe) {
  bool isb = probe_is_bf16(probe);
  int tg = blockIdx.x * 256 + threadIdx.x;   // 0..655359
  int row_all = tg / 5;                      // 0..131071
  int p = tg - row_all * 5;                  // 0..4
  int which = row_all >> 16;                 // 0 = Q, 1 = K
  int r = row_all & 65535;                   // bh*1024 + s
  int s = r & 1023;
  short* ptr = (which ? Kw : Qw) + (size_t)r * HDP;
  float scale = which ? 1.0f : SCALE_F;
  int d0 = p * 8, d1 = 40 + p * 8;
  short8 a = *(const short8*)&ptr[d0];
  short8 b = *(const short8*)&ptr[d1];
  float c0[8], s0[8], c1[8], s1[8];
  if (isb) {
    const short* cb = (const short*)cosb + s * 80;
    const short* sb = (const short*)sinb + s * 80;
    short8 vc0 = *(const short8*)&cb[d0];
    short8 vs0 = *(const short8*)&sb[d0];
    short8 vc1 = *(const short8*)&cb[d1];
    short8 vs1 = *(const short8*)&sb[d1];
#pragma unroll
    for (int j = 0; j < 8; j++) {
      c0[j] = bf2f(vc0[j]); s0[j] = bf2f(vs0[j]);
      c1[j] = bf2f(vc1[j]); s1[j] = bf2f(vs1[j]);
    }
  } else {
    const float* cb = (const float*)cosb + s * 80;
    const float* sb = (const float*)sinb + s * 80;
    float4 vc0a = *(const float4*)&cb[d0];
    float4 vc0b = *(const float4*)&cb[d0 + 4];
    float4 vs0a = *(const float4*)&sb[d0];
    float4 vs0b = *(const float4*)&sb[d0 + 4];
    float4 vc1a = *(const float4*)&cb[d1];
    float4 vc1b = *(const float4*)&cb[d1 + 4];
    float4 vs1a = *(const float4*)&sb[d1];
    float4 vs1b = *(const float4*)&sb[d1 + 4];
    c0[0] = vc0a.x; c0[1] = vc0a.y; c0[2] = vc0a.z; c0[3] = vc0a.w;
    c0[4] = vc0b.x; c0[5] = vc0b.y; c0[6] = vc0b.z; c0[7] = vc0b.w;
    s0[0] = vs0a.x; s0[1] = vs0a.y; s0[2] = vs0a.z; s0[3] = vs0a.w;
    s0[4] = vs0b.x; s0[5] = vs0b.y; s0[6] = vs0b.z; s0[7] = vs0b.w;
    c1[0] = vc1a.x; c1[1] = vc1a.y; c1[2] = vc1a.z; c1[3] = vc1a.w;
    c1[4] = vc1b.x; c1[5] = vc1b.y; c1[6] = vc1b.z; c1[7] = vc1b.w;
    s1[0] = vs1a.x; s1[1] = vs1a.y; s1[2] = vs1a.z; s1[3] = vs1a.w;
    s1[4] = vs1b.x; s1[5] = vs1b.y; s1[6] = vs1b.z; s1[7] = vs1b.w;
  }
  short8 o0, o1;
#pragma unroll
  for (int j = 0; j < 8; j++) {
    float av = bf2f(a[j]), bv = bf2f(b[j]);
    o0[j] = f2b((av * c0[j] - bv * s0[j]) * scale);
    o1[j] = f2b((bv * c1[j] + av * s1[j]) * scale);
  }
  *(short8*)&ptr[d0] = o0;
  *(short8*)&ptr[d1] = o1;
  if (p == 0) {
    short8 z = {};
    *(short8*)&ptr[80] = z;
    *(short8*)&ptr[88] = z;
  }
}

// ---------------------------------------------------------------- attention
// r9 (verified): swapped QK^T -> P stays in registers; double-buffered K/V,
// one barrier per chunk.
__global__ __launch_bounds__(512, 4) void attn_kernel(
    const short* __restrict__ Qw, const short* __restrict__ Kw,
    const short* __restrict__ Vt, short* __restrict__ out) {
  __shared__ short Klds[2][64 * 104];
  __shared__ short Vlds[2][80 * 72];
  int t = threadIdx.x;
  int w = t >> 6, lane = t & 63;
  int quad = lane >> 4, l16 = lane & 15;
  int bh = blockIdx.x & 63;        // XCD swizzle: same bh -> same XCD
  int qt = blockIdx.x >> 6;        // 0..7
  int q0 = qt * 128;
  const short* Kb = Kw + (size_t)bh * 1024 * HDP;
  const short* Vb = Vt + (size_t)bh * 80 * 1024;

  short8 aq[3];
  {
    const short* qrow = Qw + ((size_t)bh * 1024 + q0 + w * 16 + l16) * HDP;
#pragma unroll
    for (int ks = 0; ks < 3; ks++)
      aq[ks] = *(const short8*)&qrow[ks * 32 + quad * 8];
  }

  short8 kreg[2], vreg[2];
#define PREFETCH(c)                                                        \
  {                                                                        \
    {                                                                      \
      int row = t / 12, col = (t % 12) * 8;                                \
      kreg[0] = *(const short8*)&Kb[(size_t)((c) + row) * HDP + col];      \
    }                                                                      \
    if (t < 256) {                                                         \
      int idx = 512 + t;                                                   \
      int row = idx / 12, col = (idx % 12) * 8;                            \
      kreg[1] = *(const short8*)&Kb[(size_t)((c) + row) * HDP + col];      \
    }                                                                      \
    {                                                                      \
      int d = t >> 3, s0 = (t & 7) * 8;                                    \
      vreg[0] = *(const short8*)&Vb[(size_t)d * 1024 + (c) + s0];          \
    }                                                                      \
    if (t < 128) {                                                         \
      int idx = 512 + t;                                                   \
      int d = idx >> 3, s0 = (idx & 7) * 8;                                \
      vreg[1] = *(const short8*)&Vb[(size_t)d * 1024 + (c) + s0];          \
    }                                                                      \
  }
#define STORE_LDS(P)                                                       \
  {                                                                        \
    {                                                                      \
      int row = t / 12, col = (t % 12) * 8;                                \
      *(short8*)&Klds[P][row * 104 + col] = kreg[0];                       \
    }                                                                      \
    if (t < 256) {                                                         \
      int idx = 512 + t;                                                   \
      int row = idx / 12, col = (idx % 12) * 8;                            \
      *(short8*)&Klds[P][row * 104 + col] = kreg[1];                       \
    }                                                                      \
    {                                                                      \
      int d = t >> 3, s0 = (t & 7) * 8;                                    \
      *(short8*)&Vlds[P][d * 72 + s0] = vreg[0];                           \
    }                                                                      \
    if (t < 128) {                                                         \
      int idx = 512 + t;                                                   \
      int d = idx >> 3, s0 = (idx & 7) * 8;                                \
      *(short8*)&Vlds[P][d * 72 + s0] = vreg[1];                           \
    }                                                                      \
  }

  PREFETCH(0);
  STORE_LDS(0);
  __syncthreads();

  f32x4 ofr[5] = {};
  float lsum = 0.f;

  int p = 0;
  for (int c = 0; c < 1024; c += 64, p ^= 1) {
    if (c + 64 < 1024) PREFETCH(c + 64);   // global loads fly under compute
    const short* Kl = &Klds[p][0];
    const short* Vl = &Vlds[p][0];
    f32x4 sf[4] = {};
#pragma unroll
    for (int nt = 0; nt < 4; nt++) {
      short8 bk0 = *(const short8*)&Kl[(nt * 16 + l16) * 104 + 0 * 32 + quad * 8];
      short8 bk1 = *(const short8*)&Kl[(nt * 16 + l16) * 104 + 1 * 32 + quad * 8];
      short8 bk2 = *(const short8*)&Kl[(nt * 16 + l16) * 104 + 2 * 32 + quad * 8];
      sf[nt] = MFMA(bk0, aq[0], sf[nt]);   // A=K (rows kv), B=Q (cols q)
      sf[nt] = MFMA(bk1, aq[1], sf[nt]);
      sf[nt] = MFMA(bk2, aq[2], sf[nt]);
    }
    short4v bp[4];
#pragma unroll
    for (int nt = 0; nt < 4; nt++) {
      float e0 = __expf(fminf(sf[nt][0], 30.f));
      float e1 = __expf(fminf(sf[nt][1], 30.f));
      float e2 = __expf(fminf(sf[nt][2], 30.f));
      float e3 = __expf(fminf(sf[nt][3], 30.f));
      lsum += (e0 + e1) + (e2 + e3);
      bp[nt][0] = f2b(e0); bp[nt][1] = f2b(e1);
      bp[nt][2] = f2b(e2); bp[nt][3] = f2b(e3);
    }
#pragma unroll
    for (int cc = 0; cc < 4; cc++)
#pragma unroll
      for (int nt5 = 0; nt5 < 5; nt5++) {
        short4v va =
            *(const short4v*)&Vl[(nt5 * 16 + l16) * 72 + cc * 16 + quad * 4];
        ofr[nt5] = MFMA16(va, bp[cc], ofr[nt5]);
      }
    if (c + 64 < 1024) {
      STORE_LDS(p ^ 1);       // idle buffer; readers of it passed last barrier
      __syncthreads();        // publish + close this iter's reads of buf p
    }
  }
  lsum += __shfl_xor(lsum, 16);
  lsum += __shfl_xor(lsum, 32);
  float inv = 1.f / lsum;
  int b = bh >> 4, h = bh & 15;
  int s = q0 + w * 16 + l16;
#pragma unroll
  for (int nt5 = 0; nt5 < 5; nt5++) {
    short4v o;
#pragma unroll
    for (int j = 0; j < 4; j++) o[j] = f2b(ofr[nt5][j] * inv);
    *(short4v*)&out[((size_t)(b * 1024 + s)) * 1280 + h * 80 + nt5 * 16 +
                    quad * 4] = o;
  }
}

// ---------------------------------------------------------------- proj GEMM
__global__ __launch_bounds__(256) void gemm_proj_kernel(
    const short* __restrict__ A, const short* __restrict__ Wt,
    const void* __restrict__ bias, const unsigned* __restrict__ probe,
    float* __restrict__ out) {
  const int K = 1280;
  __shared__ short As[2][128 * 32];
  __shared__ short Bs[2][128 * 32];
  int t = threadIdx.x;
  int bm = blockIdx.x / 10;
  int bn = blockIdx.x % 10;
  int m0 = bm * 128, n0 = bn * 128;
  int w = t >> 6, lane = t & 63;
  int wm = w & 1, wn = w >> 1;
  int quad = lane >> 4, l16 = lane & 15;
  int row = t >> 2, ch = (t & 3) * 8, row2 = row + 64;
  int t8 = t * 8;
  const short* Ar  = A  + (size_t)(m0 + row)  * K + ch;
  const short* Ar2 = A  + (size_t)(m0 + row2) * K + ch;
  const short* Wr  = Wt + (size_t)(n0 + row)  * K + ch;
  const short* Wr2 = Wt + (size_t)(n0 + row2) * K + ch;
  f32x4 acc[4][4] = {};
  gload_lds16(Ar,  &As[0][t8]);
  gload_lds16(Ar2, &As[0][t8 + 2048]);
  gload_lds16(Wr,  &Bs[0][t8]);
  gload_lds16(Wr2, &Bs[0][t8 + 2048]);
  __syncthreads();
  int p = 0;
#define PROJ_COMPUTE(pp)                                                      \
  {                                                                           \
    short8 af[4], bfr[4];                                                     \
    _Pragma("unroll") for (int mt = 0; mt < 4; mt++)                          \
        af[mt] = *(const short8*)&As[pp][(wm * 64 + mt * 16 + l16) * 32 + quad * 8]; \
    _Pragma("unroll") for (int nt = 0; nt < 4; nt++)                          \
        bfr[nt] = *(const short8*)&Bs[pp][(wn * 64 + nt * 16 + l16) * 32 + quad * 8]; \
    _Pragma("unroll") for (int mt = 0; mt < 4; mt++)                          \
        _Pragma("unroll") for (int nt = 0; nt < 4; nt++)                      \
            acc[mt][nt] = MFMA(af[mt], bfr[nt], acc[mt][nt]);                 \
  }
  for (int k0 = 32; k0 < K; k0 += 32, p ^= 1) {
    gload_lds16(Ar + k0,  &As[p ^ 1][t8]);
    gload_lds16(Ar2 + k0, &As[p ^ 1][t8 + 2048]);
    gload_lds16(Wr + k0,  &Bs[p ^ 1][t8]);
    gload_lds16(Wr2 + k0, &Bs[p ^ 1][t8 + 2048]);
    PROJ_COMPUTE(p);
    __syncthreads();
  }
  PROJ_COMPUTE(p);
  bool isb = probe_is_bf16(probe);
  float bv[4];
#pragma unroll
  for (int nt = 0; nt < 4; nt++)
    bv[nt] = load_scalar(bias, n0 + wn * 64 + nt * 16 + l16, isb);
#pragma unroll
  for (int mt = 0; mt < 4; mt++) {
#pragma unroll
    for (int nt = 0; nt < 4; nt++) {
      int n = n0 + wn * 64 + nt * 16 + l16;
#pragma unroll
      for (int reg = 0; reg < 4; reg++) {
        int m = m0 + wm * 64 + mt * 16 + quad * 4 + reg;
        out[(size_t)m * 1280 + n] = acc[mt][nt][reg] + bv[nt];  // FP32 store
      }
    }
  }
}

extern "C" void kernel_launch(void* const* d_in, const int* in_sizes, int n_in,
                              void* d_out, int out_size, void* d_ws, size_t ws_size,
                              hipStream_t stream) {
  const void* x        = d_in[0];
  const void* rope_cos = d_in[1];
  const void* rope_sin = d_in[2];
  const void* Wqkv     = d_in[3];
  const void* bqkv     = d_in[4];
  const void* Wproj    = d_in[5];
  const void* bproj    = d_in[6];
  const unsigned* probe = (const unsigned*)rope_cos;
  char* ws = (char*)d_ws;
  short* Wt1 = (short*)(ws + 0);          // 1280*3840*2 = 9,830,400
  short* Wt2 = (short*)(ws + 9830400);    // 1280*1280*2 = 3,276,800
  short* Qw  = (short*)(ws + 13107200);   // 64*1024*96*2 = 12,582,912
  short* Kw  = (short*)(ws + 25690112);   // 12,582,912
  short* Vt  = (short*)(ws + 38273024);   // 64*1024*80*2 = 10,485,760
  short* Xb  = (short*)(ws + 48758784);   // 4096*1280*2 = 10,485,760
  short* At  = (short*)(ws + 48758784);   // aliases Xb (disjoint lifetimes)

  preproc_kernel<<<2560 + 6400, 256, 0, stream>>>(x, Xb, Wqkv, Wt1, Wproj, Wt2,
                                                  probe);
  gemm_qkv_kernel<<<240, 512, 0, stream>>>(Xb, Wt1, bqkv, probe, Qw, Kw, Vt);
  rope_kernel<<<2560, 256, 0, stream>>>(Qw, Kw, rope_cos, rope_sin, probe);
  attn_kernel<<<512, 512, 0, stream>>>(Qw, Kw, Vt, At);
  gemm_proj_kernel<<<32 * 10, 256, 0, stream>>>(At, Wt2, bproj, probe, (float*)d_out);
}

// Round 16
// 227.907 us; speedup vs baseline: 1.0266x; 1.0203x over previous
//
#include <hip/hip_runtime.h>
#include <math.h>

// Problem constants: B=4, S=1024, DIM=1280, H=16, HD=80
// Inputs fp32 (runtime-probed); OUTPUT FP32.
#define SCALE_F 0.11180339887498949f   // 80^-0.5
#define HDP 96                          // HD padded to multiple of 32 for QK^T

typedef short  short8  __attribute__((ext_vector_type(8)));
typedef short  short4v __attribute__((ext_vector_type(4)));
typedef float  f32x4   __attribute__((ext_vector_type(4)));
typedef __bf16 bf16x8  __attribute__((ext_vector_type(8)));
typedef __bf16 bf16x4  __attribute__((ext_vector_type(4)));

__device__ __forceinline__ float bf2f(short s) {
  union { unsigned u; float f; } v;
  v.u = ((unsigned)(unsigned short)s) << 16;
  return v.f;
}
__device__ __forceinline__ short f2b(float f) {
  __bf16 h = (__bf16)f;
  return __builtin_bit_cast(short, h);
}
__device__ __forceinline__ bool probe_is_bf16(const unsigned* probe) {
  return (probe[1] & 0xFFFFu) != 0u;
}
__device__ __forceinline__ float load_scalar(const void* p, int i, bool isb) {
  return isb ? bf2f(((const short*)p)[i]) : ((const float*)p)[i];
}

// async global->LDS, 16B per lane. HW LDS placement: wave-uniform base +
// lane*16 (m104/m108); per-lane pointer below coincides with that exactly.
__device__ __forceinline__ void gload_lds16(const short* g, short* l) {
  __builtin_amdgcn_global_load_lds(
      (const __attribute__((address_space(1))) void*)g,
      (__attribute__((address_space(3))) void*)l, 16, 0, 0);
}

template <typename V>
__device__ __forceinline__ auto mfma_try(V a, V b, f32x4 c, int)
    -> decltype(__builtin_amdgcn_mfma_f32_16x16x32_bf16(a, b, c, 0, 0, 0)) {
  return __builtin_amdgcn_mfma_f32_16x16x32_bf16(a, b, c, 0, 0, 0);
}
template <typename V>
__device__ __forceinline__ f32x4 mfma_try(V a, V b, f32x4 c, long) {
  return __builtin_amdgcn_mfma_f32_16x16x32_bf16(
      __builtin_bit_cast(bf16x8, a), __builtin_bit_cast(bf16x8, b), c, 0, 0, 0);
}
__device__ __forceinline__ f32x4 MFMA(short8 a, short8 b, f32x4 c) {
  return mfma_try(a, b, c, 0);
}

// 16x16x16 bf16 MFMA (k=16): A/B = 4 bf16 (2 VGPRs), C/D = f32x4.
// Builtin name varies across ROCm; 3-way guarded.
#if __has_builtin(__builtin_amdgcn_mfma_f32_16x16x16bf16_1k)
template <typename V>
__device__ __forceinline__ auto mfma16_try(V a, V b, f32x4 c, int)
    -> decltype(__builtin_amdgcn_mfma_f32_16x16x16bf16_1k(a, b, c, 0, 0, 0)) {
  return __builtin_amdgcn_mfma_f32_16x16x16bf16_1k(a, b, c, 0, 0, 0);
}
template <typename V>
__device__ __forceinline__ f32x4 mfma16_try(V a, V b, f32x4 c, long) {
  return __builtin_amdgcn_mfma_f32_16x16x16bf16_1k(
      __builtin_bit_cast(bf16x4, a), __builtin_bit_cast(bf16x4, b), c, 0, 0, 0);
}
__device__ __forceinline__ f32x4 MFMA16(short4v a, short4v b, f32x4 c) {
  return mfma16_try(a, b, c, 0);
}
#elif __has_builtin(__builtin_amdgcn_mfma_f32_16x16x16_bf16)
template <typename V>
__device__ __forceinline__ auto mfma16_try(V a, V b, f32x4 c, int)
    -> decltype(__builtin_amdgcn_mfma_f32_16x16x16_bf16(a, b, c, 0, 0, 0)) {
  return __builtin_amdgcn_mfma_f32_16x16x16_bf16(a, b, c, 0, 0, 0);
}
template <typename V>
__device__ __forceinline__ f32x4 mfma16_try(V a, V b, f32x4 c, long) {
  return __builtin_amdgcn_mfma_f32_16x16x16_bf16(
      __builtin_bit_cast(bf16x4, a), __builtin_bit_cast(bf16x4, b), c, 0, 0, 0);
}
__device__ __forceinline__ f32x4 MFMA16(short4v a, short4v b, f32x4 c) {
  return mfma16_try(a, b, c, 0);
}
#else
__device__ __forceinline__ f32x4 MFMA16(short4v a, short4v b, f32x4 c) {
  asm volatile("v_mfma_f32_16x16x16_bf16 %0, %1, %2, %0"
               : "+v"(c) : "v"(a), "v"(b));
  return c;
}
#endif

// ------------------------------------------------ fused preprocessing
// r15 (verified): one launch replaces {cvt_x, transpose(Wqkv),
// transpose(Wproj)}; dtype dispatch device-side via probe.
__global__ __launch_bounds__(256) void preproc_kernel(
    const void* __restrict__ xin, short* __restrict__ xout,
    const void* __restrict__ wqkv, short* __restrict__ wt1,
    const void* __restrict__ wproj, short* __restrict__ wt2,
    const unsigned* __restrict__ probe) {
  __shared__ float tile[32][33];
  bool isb = probe_is_bf16(probe);
  int bid = blockIdx.x;
  int t = threadIdx.x;
  if (bid < 2560) {  // ---- cvt_x: fp32 -> bf16 (or copy) ----
    size_t i = ((size_t)bid * 256 + t) * 8;
    if (isb) {
      *(short8*)&xout[i] = *(const short8*)((const short*)xin + i);
    } else {
      const float* f = (const float*)xin + i;
      float4 a0 = *(const float4*)f;
      float4 a1 = *(const float4*)(f + 4);
      short8 sv;
      sv[0] = f2b(a0.x); sv[1] = f2b(a0.y); sv[2] = f2b(a0.z); sv[3] = f2b(a0.w);
      sv[4] = f2b(a1.x); sv[5] = f2b(a1.y); sv[6] = f2b(a1.z); sv[7] = f2b(a1.w);
      *(short8*)&xout[i] = sv;
    }
    return;
  }
  // ---- weight transposes ----
  int b2 = bid - 2560;
  const void* in; short* out; int R, C, bx, by;
  if (b2 < 4800) {
    in = wqkv; out = wt1; R = 1280; C = 3840;
    bx = b2 % 120; by = b2 / 120;
  } else {
    int b3 = b2 - 4800;
    in = wproj; out = wt2; R = 1280; C = 1280;
    bx = b3 % 40; by = b3 / 40;
  }
  int r = t >> 3, c4 = (t & 7) * 4;
  size_t idx = (size_t)(by * 32 + r) * C + bx * 32 + c4;
  if (isb) {
    short4v v = *(const short4v*)((const short*)in + idx);
    tile[r][c4 + 0] = bf2f(v[0]);
    tile[r][c4 + 1] = bf2f(v[1]);
    tile[r][c4 + 2] = bf2f(v[2]);
    tile[r][c4 + 3] = bf2f(v[3]);
  } else {
    float4 v = *(const float4*)((const float*)in + idx);
    tile[r][c4 + 0] = v.x;
    tile[r][c4 + 1] = v.y;
    tile[r][c4 + 2] = v.z;
    tile[r][c4 + 3] = v.w;
  }
  __syncthreads();
  int rr = t >> 3, k4 = (t & 7) * 4;
  short4v o;
  o[0] = f2b(tile[k4 + 0][rr]);
  o[1] = f2b(tile[k4 + 1][rr]);
  o[2] = f2b(tile[k4 + 2][rr]);
  o[3] = f2b(tile[k4 + 3][rr]);
  *(short4v*)&out[(size_t)(bx * 32 + rr) * R + by * 32 + k4] = o;
}

// ---------------------------------------------------------------- QKV GEMM
// r11 structure (best measured 49.4-50.4 µs): 256x256, BK=64, 8 waves,
// 4 merged phases / 2 K-tiles, T2 swizzle (0 conflicts), counted vmcnt,
// register-hoisted fragments.
__global__ __launch_bounds__(512, 2) void gemm_qkv_kernel(
    const short* __restrict__ X, const short* __restrict__ Wt,
    const void* __restrict__ bias, const unsigned* __restrict__ probe,
    short* __restrict__ Qw, short* __restrict__ Kw, short* __restrict__ Vt) {
  const int K = 1280;
  __shared__ short Al[2][2][8192];   // [slot][half][128*64]
  __shared__ short Bl[2][2][8192];
  int t = threadIdx.x;
  int bm = blockIdx.x / 15, bn = blockIdx.x % 15;
  int m0 = bm * 256, n0 = bn * 256;
  int w = t >> 6, lane = t & 63;
  int quad = lane >> 4, l16 = lane & 15, l8 = l16 & 7;
  int arow = (w >> 2) * 64 + l16;   // + mt*16 -> A row within half
  int brow = (w & 3) * 32 + l16;    // + nt*16 -> B row within half
  int sr = t >> 3, t8s = t * 8;
  int sjs = (t & 7) ^ (sr & 7);     // pre-swizzled global k-slot (involution)
  int soff0 = ((quad ^ l8) * 8);
  int soff1 = (((4 + quad) ^ l8) * 8);
  f32x4 acc[2][2][4][2] = {};       // [qm][qn][mt][nt], all-static indexing
  short8 afr[4][2];                 // A fragments of current (S,HA)
  short8 bf0[2][2], bf1[2][2];      // B fragments, half0 / half1 of current S

#define STAGE8(PTR, R0, KOFF, LP)                                            \
  {                                                                          \
    const short* g_ = (PTR) + (size_t)((R0) + sr) * 1280 + (KOFF) + sjs * 8; \
    gload_lds16(g_, (LP) + t8s);                                             \
    gload_lds16(g_ + 64 * 1280, (LP) + t8s + 4096);                          \
  }

#define READ_A(S, H)                                                         \
  {                                                                          \
    _Pragma("unroll") for (int mt = 0; mt < 4; mt++) {                       \
      int rp_ = (arow + mt * 16) * 64;                                       \
      afr[mt][0] = *(const short8*)&Al[S][H][rp_ + soff0];                   \
      afr[mt][1] = *(const short8*)&Al[S][H][rp_ + soff1];                   \
    }                                                                        \
  }
#define READ_B(DST, S, H)                                                    \
  {                                                                          \
    _Pragma("unroll") for (int nt = 0; nt < 2; nt++) {                       \
      int rp_ = (brow + nt * 16) * 64;                                       \
      DST[nt][0] = *(const short8*)&Bl[S][H][rp_ + soff0];                   \
      DST[nt][1] = *(const short8*)&Bl[S][H][rp_ + soff1];                   \
    }                                                                        \
  }
// one quadrant cluster (16 MFMA) with a counted lgkm wait before it
#define CLUST(QM, QN, BF, WAITI)                                             \
  {                                                                          \
    asm volatile("s_waitcnt lgkmcnt(" #WAITI ")" ::: "memory");              \
    __builtin_amdgcn_sched_barrier(0);                                       \
    _Pragma("unroll") for (int mt = 0; mt < 4; mt++)                         \
      _Pragma("unroll") for (int nt = 0; nt < 2; nt++) {                     \
        acc[QM][QN][mt][nt] = MFMA(afr[mt][0], BF[nt][0], acc[QM][QN][mt][nt]); \
        acc[QM][QN][mt][nt] = MFMA(afr[mt][1], BF[nt][1], acc[QM][QN][mt][nt]); \
      }                                                                      \
  }
#define BAR() __builtin_amdgcn_s_barrier()
#define VW4()                                                                \
  {                                                                          \
    asm volatile("s_waitcnt vmcnt(4)" ::: "memory");                         \
    __builtin_amdgcn_sched_barrier(0);                                       \
  }

  // prologue: tile0 (all 4 halves) + tile1 (A0,B0) = 12 loads/thread
  STAGE8(X,  m0,       0,  &Al[0][0][0]);
  STAGE8(X,  m0 + 128, 0,  &Al[0][1][0]);
  STAGE8(Wt, n0,       0,  &Bl[0][0][0]);
  STAGE8(Wt, n0 + 128, 0,  &Bl[0][1][0]);
  STAGE8(X,  m0,       64, &Al[1][0][0]);
  STAGE8(Wt, n0,       64, &Bl[1][0][0]);
  VW4();   // tile0's 8 loads landed
  BAR();

  for (int i = 0; i < 10; i++) {
    int k1 = (2 * i + 1) * 64;                       // <= 1216, always valid
    int k2 = (2 * i + 2) * 64; if (k2 >= K) k2 = 0;  // dummy (unread) on tail
    int k3 = (2 * i + 3) * 64; if (k3 >= K) k3 = 0;
    // ---- PhA (S=0): quadrants (0,0)+(0,1), 16 reads, 2 stage-pairs ----
    READ_A(0, 0); READ_B(bf0, 0, 0); READ_B(bf1, 0, 1);
    STAGE8(X,  m0 + 128, k1, &Al[1][1][0]);
    STAGE8(Wt, n0 + 128, k1, &Bl[1][1][0]);
    __builtin_amdgcn_s_setprio(1);
    CLUST(0, 0, bf0, 4);   // bf1's 4 reads land under this cluster
    CLUST(0, 1, bf1, 0);
    __builtin_amdgcn_s_setprio(0);
    BAR();
    // ---- PhB (S=0): quadrants (1,0)+(1,1), 8 reads ----
    READ_A(0, 1);
    STAGE8(X,  m0,       k2, &Al[0][0][0]);
    STAGE8(Wt, n0,       k2, &Bl[0][0][0]);
    __builtin_amdgcn_s_setprio(1);
    CLUST(1, 0, bf0, 0);
    CLUST(1, 1, bf1, 0);
    __builtin_amdgcn_s_setprio(0);
    VW4();                 // drains prevB + PhA stages -> slot1 ready
    BAR();
    // ---- PhA (S=1) ----
    READ_A(1, 0); READ_B(bf0, 1, 0); READ_B(bf1, 1, 1);
    STAGE8(X,  m0 + 128, k2, &Al[0][1][0]);
    STAGE8(Wt, n0 + 128, k2, &Bl[0][1][0]);
    __builtin_amdgcn_s_setprio(1);
    CLUST(0, 0, bf0, 4);
    CLUST(0, 1, bf1, 0);
    __builtin_amdgcn_s_setprio(0);
    BAR();
    // ---- PhB (S=1) ----
    READ_A(1, 1);
    STAGE8(X,  m0,       k3, &Al[1][0][0]);
    STAGE8(Wt, n0,       k3, &Bl[1][0][0]);
    __builtin_amdgcn_s_setprio(1);
    CLUST(1, 0, bf0, 0);
    CLUST(1, 1, bf1, 0);
    __builtin_amdgcn_s_setprio(0);
    VW4();                 // drains PhB(S=0) + PhA(S=1) stages -> slot0 ready
    BAR();
  }
  asm volatile("s_waitcnt vmcnt(0)" ::: "memory");   // drain dummy stages
  __builtin_amdgcn_sched_barrier(0);

  bool isb = probe_is_bf16(probe);
  float bv[2][2];
#pragma unroll
  for (int qn = 0; qn < 2; qn++)
#pragma unroll
    for (int nt = 0; nt < 2; nt++)
      bv[qn][nt] =
          load_scalar(bias, n0 + qn * 128 + (w & 3) * 32 + nt * 16 + l16, isb);
#pragma unroll
  for (int qm = 0; qm < 2; qm++)
#pragma unroll
    for (int mt = 0; mt < 4; mt++) {
      int mbase = m0 + qm * 128 + (w >> 2) * 64 + mt * 16 + quad * 4;
      int b = mbase >> 10, sbase = mbase & 1023;
#pragma unroll
      for (int qn = 0; qn < 2; qn++)
#pragma unroll
        for (int nt = 0; nt < 2; nt++) {
          int n = n0 + qn * 128 + (w & 3) * 32 + nt * 16 + l16;
          int which = n / 1280;
          int rmod = n - which * 1280;
          int h = rmod / 80;
          int d = rmod - h * 80;
          int bh = b * 16 + h;
          if (which == 2) {
            short4v vv;
#pragma unroll
            for (int reg = 0; reg < 4; reg++)
              vv[reg] = f2b(acc[qm][qn][mt][nt][reg] + bv[qn][nt]);
            *(short4v*)&Vt[((size_t)bh * 80 + d) * 1024 + sbase] = vv;
          } else {
            short* dst = (which == 0 ? Qw : Kw);
#pragma unroll
            for (int reg = 0; reg < 4; reg++)
              dst[((size_t)bh * 1024 + sbase + reg) * HDP + d] =
                  f2b(acc[qm][qn][mt][nt][reg] + bv[qn][nt]);
          }
        }
    }
#undef STAGE8
#undef READ_A
#undef READ_B
#undef CLUST
#undef BAR
#undef VW4
}

// ---------------------------------------------------------------- RoPE
// r10 (verified): vectorized; each thread owns chunk pair (p*8, 40+p*8).
__global__ __launch_bounds__(256) void rope_kernel(
    short* __restrict__ Qw, short* __restrict__ Kw,
    const void* __restrict__ cosb, const void* __restrict__ sinb,
    const unsigned* __restrict__ probe) {
  bool isb = probe_is_bf16(probe);
  int tg = blockIdx.x * 256 + threadIdx.x;   // 0..655359
  int row_all = tg / 5;                      // 0..131071
  int p = tg - row_all * 5;                  // 0..4
  int which = row_all >> 16;                 // 0 = Q, 1 = K
  int r = row_all & 65535;                   // bh*1024 + s
  int s = r & 1023;
  short* ptr = (which ? Kw : Qw) + (size_t)r * HDP;
  float scale = which ? 1.0f : SCALE_F;
  int d0 = p * 8, d1 = 40 + p * 8;
  short8 a = *(const short8*)&ptr[d0];
  short8 b = *(const short8*)&ptr[d1];
  float c0[8], s0[8], c1[8], s1[8];
  if (isb) {
    const short* cb = (const short*)cosb + s * 80;
    const short* sb = (const short*)sinb + s * 80;
    short8 vc0 = *(const short8*)&cb[d0];
    short8 vs0 = *(const short8*)&sb[d0];
    short8 vc1 = *(const short8*)&cb[d1];
    short8 vs1 = *(const short8*)&sb[d1];
#pragma unroll
    for (int j = 0; j < 8; j++) {
      c0[j] = bf2f(vc0[j]); s0[j] = bf2f(vs0[j]);
      c1[j] = bf2f(vc1[j]); s1[j] = bf2f(vs1[j]);
    }
  } else {
    const float* cb = (const float*)cosb + s * 80;
    const float* sb = (const float*)sinb + s * 80;
    float4 vc0a = *(const float4*)&cb[d0];
    float4 vc0b = *(const float4*)&cb[d0 + 4];
    float4 vs0a = *(const float4*)&sb[d0];
    float4 vs0b = *(const float4*)&sb[d0 + 4];
    float4 vc1a = *(const float4*)&cb[d1];
    float4 vc1b = *(const float4*)&cb[d1 + 4];
    float4 vs1a = *(const float4*)&sb[d1];
    float4 vs1b = *(const float4*)&sb[d1 + 4];
    c0[0] = vc0a.x; c0[1] = vc0a.y; c0[2] = vc0a.z; c0[3] = vc0a.w;
    c0[4] = vc0b.x; c0[5] = vc0b.y; c0[6] = vc0b.z; c0[7] = vc0b.w;
    s0[0] = vs0a.x; s0[1] = vs0a.y; s0[2] = vs0a.z; s0[3] = vs0a.w;
    s0[4] = vs0b.x; s0[5] = vs0b.y; s0[6] = vs0b.z; s0[7] = vs0b.w;
    c1[0] = vc1a.x; c1[1] = vc1a.y; c1[2] = vc1a.z; c1[3] = vc1a.w;
    c1[4] = vc1b.x; c1[5] = vc1b.y; c1[6] = vc1b.z; c1[7] = vc1b.w;
    s1[0] = vs1a.x; s1[1] = vs1a.y; s1[2] = vs1a.z; s1[3] = vs1a.w;
    s1[4] = vs1b.x; s1[5] = vs1b.y; s1[6] = vs1b.z; s1[7] = vs1b.w;
  }
  short8 o0, o1;
#pragma unroll
  for (int j = 0; j < 8; j++) {
    float av = bf2f(a[j]), bv = bf2f(b[j]);
    o0[j] = f2b((av * c0[j] - bv * s0[j]) * scale);
    o1[j] = f2b((bv * c1[j] + av * s1[j]) * scale);
  }
  *(short8*)&ptr[d0] = o0;
  *(short8*)&ptr[d1] = o1;
  if (p == 0) {
    short8 z = {};
    *(short8*)&ptr[80] = z;
    *(short8*)&ptr[88] = z;
  }
}

// ---------------------------------------------------------------- attention
// r16: 32 q-rows per wave (two 16-row groups) -> per-wave K/V LDS reads
// serve 2x the MFMA; block-level LDS traffic halves (was 8 waves x 16 rows
// redundantly reading the same shared K/V tile; now 4 waves x 32 rows).
// 256 threads, grid unchanged (512 = 64 bh x 8 qt x 128 rows). Staging
// macros are the r0-r5-verified 256-thread kreg[3]/vreg[3] pattern.
// Swapped QK^T + in-register P (r9, verified); double-buffered K/V, one
// barrier per chunk (r6, verified).
__global__ __launch_bounds__(256, 2) void attn_kernel(
    const short* __restrict__ Qw, const short* __restrict__ Kw,
    const short* __restrict__ Vt, short* __restrict__ out) {
  __shared__ short Klds[2][64 * 104];
  __shared__ short Vlds[2][80 * 72];
  int t = threadIdx.x;
  int w = t >> 6, lane = t & 63;
  int quad = lane >> 4, l16 = lane & 15;
  int bh = blockIdx.x & 63;        // XCD swizzle: same bh -> same XCD
  int qt = blockIdx.x >> 6;        // 0..7
  int q0 = qt * 128;
  const short* Kb = Kw + (size_t)bh * 1024 * HDP;
  const short* Vb = Vt + (size_t)bh * 80 * 1024;

  // Q fragments for both 16-row groups (rows q0 + w*32 + g*16 + l16)
  short8 aq0[3], aq1[3];
  {
    const short* qr0 = Qw + ((size_t)bh * 1024 + q0 + w * 32 + l16) * HDP;
    const short* qr1 = qr0 + 16 * HDP;
#pragma unroll
    for (int ks = 0; ks < 3; ks++) {
      aq0[ks] = *(const short8*)&qr0[ks * 32 + quad * 8];
      aq1[ks] = *(const short8*)&qr1[ks * 32 + quad * 8];
    }
  }

  // staging with 256 threads: K 64x96 = 768 slots (3/thread); V 80x64 =
  // 640 slots (2.5/thread)
  short8 kreg[3], vreg[3];
#define PREFETCH(c)                                                        \
  {                                                                        \
    _Pragma("unroll") for (int i = 0; i < 3; i++) {                        \
      int idx = i * 256 + t;                                               \
      int row = idx / 12, col = (idx % 12) * 8;                            \
      kreg[i] = *(const short8*)&Kb[(size_t)((c) + row) * HDP + col];      \
    }                                                                      \
    _Pragma("unroll") for (int i = 0; i < 3; i++) {                        \
      int idx = i * 256 + t;                                               \
      if (idx < 640) {                                                     \
        int d = idx >> 3, s0 = (idx & 7) * 8;                              \
        vreg[i] = *(const short8*)&Vb[(size_t)d * 1024 + (c) + s0];        \
      }                                                                    \
    }                                                                      \
  }
#define STORE_LDS(P)                                                       \
  {                                                                        \
    _Pragma("unroll") for (int i = 0; i < 3; i++) {                        \
      int idx = i * 256 + t;                                               \
      int row = idx / 12, col = (idx % 12) * 8;                            \
      *(short8*)&Klds[P][row * 104 + col] = kreg[i];                       \
    }                                                                      \
    _Pragma("unroll") for (int i = 0; i < 3; i++) {                        \
      int idx = i * 256 + t;                                               \
      if (idx < 640) {                                                     \
        int d = idx >> 3, s0 = (idx & 7) * 8;                              \
        *(short8*)&Vlds[P][d * 72 + s0] = vreg[i];                         \
      }                                                                    \
    }                                                                      \
  }

  PREFETCH(0);
  STORE_LDS(0);
  __syncthreads();

  f32x4 ofr0[5] = {}, ofr1[5] = {};
  float lsum0 = 0.f, lsum1 = 0.f;

  int p = 0;
  for (int c = 0; c < 1024; c += 64, p ^= 1) {
    if (c + 64 < 1024) PREFETCH(c + 64);   // global loads fly under compute
    const short* Kl = &Klds[p][0];
    const short* Vl = &Vlds[p][0];
    // swapped QK^T, both q-groups share the K fragments (12 reads -> 24 MFMA)
    f32x4 sf0[4] = {}, sf1[4] = {};
#pragma unroll
    for (int nt = 0; nt < 4; nt++) {
      short8 bk0 = *(const short8*)&Kl[(nt * 16 + l16) * 104 + 0 * 32 + quad * 8];
      short8 bk1 = *(const short8*)&Kl[(nt * 16 + l16) * 104 + 1 * 32 + quad * 8];
      short8 bk2 = *(const short8*)&Kl[(nt * 16 + l16) * 104 + 2 * 32 + quad * 8];
      sf0[nt] = MFMA(bk0, aq0[0], sf0[nt]);
      sf1[nt] = MFMA(bk0, aq1[0], sf1[nt]);
      sf0[nt] = MFMA(bk1, aq0[1], sf0[nt]);
      sf1[nt] = MFMA(bk1, aq1[1], sf1[nt]);
      sf0[nt] = MFMA(bk2, aq0[2], sf0[nt]);
      sf1[nt] = MFMA(bk2, aq1[2], sf1[nt]);
    }
    // unsafe softmax in-register, both groups
    short4v bp0[4], bp1[4];
#pragma unroll
    for (int nt = 0; nt < 4; nt++) {
      float e0 = __expf(fminf(sf0[nt][0], 30.f));
      float e1 = __expf(fminf(sf0[nt][1], 30.f));
      float e2 = __expf(fminf(sf0[nt][2], 30.f));
      float e3 = __expf(fminf(sf0[nt][3], 30.f));
      lsum0 += (e0 + e1) + (e2 + e3);
      bp0[nt][0] = f2b(e0); bp0[nt][1] = f2b(e1);
      bp0[nt][2] = f2b(e2); bp0[nt][3] = f2b(e3);
      float f0 = __expf(fminf(sf1[nt][0], 30.f));
      float f1 = __expf(fminf(sf1[nt][1], 30.f));
      float f2 = __expf(fminf(sf1[nt][2], 30.f));
      float f3 = __expf(fminf(sf1[nt][3], 30.f));
      lsum1 += (f0 + f1) + (f2 + f3);
      bp1[nt][0] = f2b(f0); bp1[nt][1] = f2b(f1);
      bp1[nt][2] = f2b(f2); bp1[nt][3] = f2b(f3);
    }
    // PV: each V fragment read feeds both groups (20 reads -> 40 MFMA16)
#pragma unroll
    for (int cc = 0; cc < 4; cc++)
#pragma unroll
      for (int nt5 = 0; nt5 < 5; nt5++) {
        short4v va =
            *(const short4v*)&Vl[(nt5 * 16 + l16) * 72 + cc * 16 + quad * 4];
        ofr0[nt5] = MFMA16(va, bp0[cc], ofr0[nt5]);
        ofr1[nt5] = MFMA16(va, bp1[cc], ofr1[nt5]);
      }
    if (c + 64 < 1024) {
      STORE_LDS(p ^ 1);       // idle buffer; readers of it passed last barrier
      __syncthreads();        // publish + close this iter's reads of buf p
    }
  }
  // row sums (per group): partials live in the 4 lanes sharing l16
  lsum0 += __shfl_xor(lsum0, 16);
  lsum0 += __shfl_xor(lsum0, 32);
  lsum1 += __shfl_xor(lsum1, 16);
  lsum1 += __shfl_xor(lsum1, 32);
  float inv0 = 1.f / lsum0, inv1 = 1.f / lsum1;
  int b = bh >> 4, h = bh & 15;
  int s0r = q0 + w * 32 + l16;
  int s1r = s0r + 16;
#pragma unroll
  for (int nt5 = 0; nt5 < 5; nt5++) {
    short4v o0, o1;
#pragma unroll
    for (int j = 0; j < 4; j++) {
      o0[j] = f2b(ofr0[nt5][j] * inv0);
      o1[j] = f2b(ofr1[nt5][j] * inv1);
    }
    *(short4v*)&out[((size_t)(b * 1024 + s0r)) * 1280 + h * 80 + nt5 * 16 +
                    quad * 4] = o0;
    *(short4v*)&out[((size_t)(b * 1024 + s1r)) * 1280 + h * 80 + nt5 * 16 +
                    quad * 4] = o1;
  }
}

// ---------------------------------------------------------------- proj GEMM
__global__ __launch_bounds__(256) void gemm_proj_kernel(
    const short* __restrict__ A, const short* __restrict__ Wt,
    const void* __restrict__ bias, const unsigned* __restrict__ probe,
    float* __restrict__ out) {
  const int K = 1280;
  __shared__ short As[2][128 * 32];
  __shared__ short Bs[2][128 * 32];
  int t = threadIdx.x;
  int bm = blockIdx.x / 10;
  int bn = blockIdx.x % 10;
  int m0 = bm * 128, n0 = bn * 128;
  int w = t >> 6, lane = t & 63;
  int wm = w & 1, wn = w >> 1;
  int quad = lane >> 4, l16 = lane & 15;
  int row = t >> 2, ch = (t & 3) * 8, row2 = row + 64;
  int t8 = t * 8;
  const short* Ar  = A  + (size_t)(m0 + row)  * K + ch;
  const short* Ar2 = A  + (size_t)(m0 + row2) * K + ch;
  const short* Wr  = Wt + (size_t)(n0 + row)  * K + ch;
  const short* Wr2 = Wt + (size_t)(n0 + row2) * K + ch;
  f32x4 acc[4][4] = {};
  gload_lds16(Ar,  &As[0][t8]);
  gload_lds16(Ar2, &As[0][t8 + 2048]);
  gload_lds16(Wr,  &Bs[0][t8]);
  gload_lds16(Wr2, &Bs[0][t8 + 2048]);
  __syncthreads();
  int p = 0;
#define PROJ_COMPUTE(pp)                                                      \
  {                                                                           \
    short8 af[4], bfr[4];                                                     \
    _Pragma("unroll") for (int mt = 0; mt < 4; mt++)                          \
        af[mt] = *(const short8*)&As[pp][(wm * 64 + mt * 16 + l16) * 32 + quad * 8]; \
    _Pragma("unroll") for (int nt = 0; nt < 4; nt++)                          \
        bfr[nt] = *(const short8*)&Bs[pp][(wn * 64 + nt * 16 + l16) * 32 + quad * 8]; \
    _Pragma("unroll") for (int mt = 0; mt < 4; mt++)                          \
        _Pragma("unroll") for (int nt = 0; nt < 4; nt++)                      \
            acc[mt][nt] = MFMA(af[mt], bfr[nt], acc[mt][nt]);                 \
  }
  for (int k0 = 32; k0 < K; k0 += 32, p ^= 1) {
    gload_lds16(Ar + k0,  &As[p ^ 1][t8]);
    gload_lds16(Ar2 + k0, &As[p ^ 1][t8 + 2048]);
    gload_lds16(Wr + k0,  &Bs[p ^ 1][t8]);
    gload_lds16(Wr2 + k0, &Bs[p ^ 1][t8 + 2048]);
    PROJ_COMPUTE(p);
    __syncthreads();
  }
  PROJ_COMPUTE(p);
  bool isb = probe_is_bf16(probe);
  float bv[4];
#pragma unroll
  for (int nt = 0; nt < 4; nt++)
    bv[nt] = load_scalar(bias, n0 + wn * 64 + nt * 16 + l16, isb);
#pragma unroll
  for (int mt = 0; mt < 4; mt++) {
#pragma unroll
    for (int nt = 0; nt < 4; nt++) {
      int n = n0 + wn * 64 + nt * 16 + l16;
#pragma unroll
      for (int reg = 0; reg < 4; reg++) {
        int m = m0 + wm * 64 + mt * 16 + quad * 4 + reg;
        out[(size_t)m * 1280 + n] = acc[mt][nt][reg] + bv[nt];  // FP32 store
      }
    }
  }
}

extern "C" void kernel_launch(void* const* d_in, const int* in_sizes, int n_in,
                              void* d_out, int out_size, void* d_ws, size_t ws_size,
                              hipStream_t stream) {
  const void* x        = d_in[0];
  const void* rope_cos = d_in[1];
  const void* rope_sin = d_in[2];
  const void* Wqkv     = d_in[3];
  const void* bqkv     = d_in[4];
  const void* Wproj    = d_in[5];
  const void* bproj    = d_in[6];
  const unsigned* probe = (const unsigned*)rope_cos;
  char* ws = (char*)d_ws;
  short* Wt1 = (short*)(ws + 0);          // 1280*3840*2 = 9,830,400
  short* Wt2 = (short*)(ws + 9830400);    // 1280*1280*2 = 3,276,800
  short* Qw  = (short*)(ws + 13107200);   // 64*1024*96*2 = 12,582,912
  short* Kw  = (short*)(ws + 25690112);   // 12,582,912
  short* Vt  = (short*)(ws + 38273024);   // 64*1024*80*2 = 10,485,760
  short* Xb  = (short*)(ws + 48758784);   // 4096*1280*2 = 10,485,760
  short* At  = (short*)(ws + 48758784);   // aliases Xb (disjoint lifetimes)

  preproc_kernel<<<2560 + 6400, 256, 0, stream>>>(x, Xb, Wqkv, Wt1, Wproj, Wt2,
                                                  probe);
  gemm_qkv_kernel<<<240, 512, 0, stream>>>(Xb, Wt1, bqkv, probe, Qw, Kw, Vt);
  rope_kernel<<<2560, 256, 0, stream>>>(Qw, Kw, rope_cos, rope_sin, probe);
  attn_kernel<<<512, 256, 0, stream>>>(Qw, Kw, Vt, At);
  gemm_proj_kernel<<<32 * 10, 256, 0, stream>>>(At, Wt2, bproj, probe, (float*)d_out);
}

// Round 17
// 222.221 us; speedup vs baseline: 1.0528x; 1.0256x over previous
//
#include <hip/hip_runtime.h>
#include <math.h>

// Problem constants: B=4, S=1024, DIM=1280, H=16, HD=80
// Inputs fp32 (runtime-probed); OUTPUT FP32.
#define SCALE_F 0.11180339887498949f   // 80^-0.5
#define HDP 96                          // HD padded to multiple of 32 for QK^T

typedef short  short8  __attribute__((ext_vector_type(8)));
typedef short  short4v __attribute__((ext_vector_type(4)));
typedef float  f32x4   __attribute__((ext_vector_type(4)));
typedef __bf16 bf16x8  __attribute__((ext_vector_type(8)));
typedef __bf16 bf16x4  __attribute__((ext_vector_type(4)));

__device__ __forceinline__ float bf2f(short s) {
  union { unsigned u; float f; } v;
  v.u = ((unsigned)(unsigned short)s) << 16;
  return v.f;
}
__device__ __forceinline__ short f2b(float f) {
  __bf16 h = (__bf16)f;
  return __builtin_bit_cast(short, h);
}
__device__ __forceinline__ bool probe_is_bf16(const unsigned* probe) {
  return (probe[1] & 0xFFFFu) != 0u;
}
__device__ __forceinline__ float load_scalar(const void* p, int i, bool isb) {
  return isb ? bf2f(((const short*)p)[i]) : ((const float*)p)[i];
}

// async global->LDS, 16B per lane. HW LDS placement: wave-uniform base +
// lane*16 (m104/m108); per-lane pointer below coincides with that exactly.
__device__ __forceinline__ void gload_lds16(const short* g, short* l) {
  __builtin_amdgcn_global_load_lds(
      (const __attribute__((address_space(1))) void*)g,
      (__attribute__((address_space(3))) void*)l, 16, 0, 0);
}

template <typename V>
__device__ __forceinline__ auto mfma_try(V a, V b, f32x4 c, int)
    -> decltype(__builtin_amdgcn_mfma_f32_16x16x32_bf16(a, b, c, 0, 0, 0)) {
  return __builtin_amdgcn_mfma_f32_16x16x32_bf16(a, b, c, 0, 0, 0);
}
template <typename V>
__device__ __forceinline__ f32x4 mfma_try(V a, V b, f32x4 c, long) {
  return __builtin_amdgcn_mfma_f32_16x16x32_bf16(
      __builtin_bit_cast(bf16x8, a), __builtin_bit_cast(bf16x8, b), c, 0, 0, 0);
}
__device__ __forceinline__ f32x4 MFMA(short8 a, short8 b, f32x4 c) {
  return mfma_try(a, b, c, 0);
}

// 16x16x16 bf16 MFMA (k=16): A/B = 4 bf16 (2 VGPRs), C/D = f32x4.
// Builtin name varies across ROCm; 3-way guarded.
#if __has_builtin(__builtin_amdgcn_mfma_f32_16x16x16bf16_1k)
template <typename V>
__device__ __forceinline__ auto mfma16_try(V a, V b, f32x4 c, int)
    -> decltype(__builtin_amdgcn_mfma_f32_16x16x16bf16_1k(a, b, c, 0, 0, 0)) {
  return __builtin_amdgcn_mfma_f32_16x16x16bf16_1k(a, b, c, 0, 0, 0);
}
template <typename V>
__device__ __forceinline__ f32x4 mfma16_try(V a, V b, f32x4 c, long) {
  return __builtin_amdgcn_mfma_f32_16x16x16bf16_1k(
      __builtin_bit_cast(bf16x4, a), __builtin_bit_cast(bf16x4, b), c, 0, 0, 0);
}
__device__ __forceinline__ f32x4 MFMA16(short4v a, short4v b, f32x4 c) {
  return mfma16_try(a, b, c, 0);
}
#elif __has_builtin(__builtin_amdgcn_mfma_f32_16x16x16_bf16)
template <typename V>
__device__ __forceinline__ auto mfma16_try(V a, V b, f32x4 c, int)
    -> decltype(__builtin_amdgcn_mfma_f32_16x16x16_bf16(a, b, c, 0, 0, 0)) {
  return __builtin_amdgcn_mfma_f32_16x16x16_bf16(a, b, c, 0, 0, 0);
}
template <typename V>
__device__ __forceinline__ f32x4 mfma16_try(V a, V b, f32x4 c, long) {
  return __builtin_amdgcn_mfma_f32_16x16x16_bf16(
      __builtin_bit_cast(bf16x4, a), __builtin_bit_cast(bf16x4, b), c, 0, 0, 0);
}
__device__ __forceinline__ f32x4 MFMA16(short4v a, short4v b, f32x4 c) {
  return mfma16_try(a, b, c, 0);
}
#else
__device__ __forceinline__ f32x4 MFMA16(short4v a, short4v b, f32x4 c) {
  asm volatile("v_mfma_f32_16x16x16_bf16 %0, %1, %2, %0"
               : "+v"(c) : "v"(a), "v"(b));
  return c;
}
#endif

// ------------------------------------------------ fused preprocessing
// r15 (verified): one launch replaces {cvt_x, transpose(Wqkv),
// transpose(Wproj)}; dtype dispatch device-side via probe.
__global__ __launch_bounds__(256) void preproc_kernel(
    const void* __restrict__ xin, short* __restrict__ xout,
    const void* __restrict__ wqkv, short* __restrict__ wt1,
    const void* __restrict__ wproj, short* __restrict__ wt2,
    const unsigned* __restrict__ probe) {
  __shared__ float tile[32][33];
  bool isb = probe_is_bf16(probe);
  int bid = blockIdx.x;
  int t = threadIdx.x;
  if (bid < 2560) {  // ---- cvt_x: fp32 -> bf16 (or copy) ----
    size_t i = ((size_t)bid * 256 + t) * 8;
    if (isb) {
      *(short8*)&xout[i] = *(const short8*)((const short*)xin + i);
    } else {
      const float* f = (const float*)xin + i;
      float4 a0 = *(const float4*)f;
      float4 a1 = *(const float4*)(f + 4);
      short8 sv;
      sv[0] = f2b(a0.x); sv[1] = f2b(a0.y); sv[2] = f2b(a0.z); sv[3] = f2b(a0.w);
      sv[4] = f2b(a1.x); sv[5] = f2b(a1.y); sv[6] = f2b(a1.z); sv[7] = f2b(a1.w);
      *(short8*)&xout[i] = sv;
    }
    return;
  }
  // ---- weight transposes ----
  int b2 = bid - 2560;
  const void* in; short* out; int R, C, bx, by;
  if (b2 < 4800) {
    in = wqkv; out = wt1; R = 1280; C = 3840;
    bx = b2 % 120; by = b2 / 120;
  } else {
    int b3 = b2 - 4800;
    in = wproj; out = wt2; R = 1280; C = 1280;
    bx = b3 % 40; by = b3 / 40;
  }
  int r = t >> 3, c4 = (t & 7) * 4;
  size_t idx = (size_t)(by * 32 + r) * C + bx * 32 + c4;
  if (isb) {
    short4v v = *(const short4v*)((const short*)in + idx);
    tile[r][c4 + 0] = bf2f(v[0]);
    tile[r][c4 + 1] = bf2f(v[1]);
    tile[r][c4 + 2] = bf2f(v[2]);
    tile[r][c4 + 3] = bf2f(v[3]);
  } else {
    float4 v = *(const float4*)((const float*)in + idx);
    tile[r][c4 + 0] = v.x;
    tile[r][c4 + 1] = v.y;
    tile[r][c4 + 2] = v.z;
    tile[r][c4 + 3] = v.w;
  }
  __syncthreads();
  int rr = t >> 3, k4 = (t & 7) * 4;
  short4v o;
  o[0] = f2b(tile[k4 + 0][rr]);
  o[1] = f2b(tile[k4 + 1][rr]);
  o[2] = f2b(tile[k4 + 2][rr]);
  o[3] = f2b(tile[k4 + 3][rr]);
  *(short4v*)&out[(size_t)(bx * 32 + rr) * R + by * 32 + k4] = o;
}

// ---------------------------------------------------------------- QKV GEMM
// r11 structure (best measured 49.4-50.4 µs): 256x256, BK=64, 8 waves,
// 4 merged phases / 2 K-tiles, T2 swizzle (0 conflicts), counted vmcnt,
// register-hoisted fragments.
__global__ __launch_bounds__(512, 2) void gemm_qkv_kernel(
    const short* __restrict__ X, const short* __restrict__ Wt,
    const void* __restrict__ bias, const unsigned* __restrict__ probe,
    short* __restrict__ Qw, short* __restrict__ Kw, short* __restrict__ Vt) {
  const int K = 1280;
  __shared__ short Al[2][2][8192];   // [slot][half][128*64]
  __shared__ short Bl[2][2][8192];
  int t = threadIdx.x;
  int bm = blockIdx.x / 15, bn = blockIdx.x % 15;
  int m0 = bm * 256, n0 = bn * 256;
  int w = t >> 6, lane = t & 63;
  int quad = lane >> 4, l16 = lane & 15, l8 = l16 & 7;
  int arow = (w >> 2) * 64 + l16;   // + mt*16 -> A row within half
  int brow = (w & 3) * 32 + l16;    // + nt*16 -> B row within half
  int sr = t >> 3, t8s = t * 8;
  int sjs = (t & 7) ^ (sr & 7);     // pre-swizzled global k-slot (involution)
  int soff0 = ((quad ^ l8) * 8);
  int soff1 = (((4 + quad) ^ l8) * 8);
  f32x4 acc[2][2][4][2] = {};       // [qm][qn][mt][nt], all-static indexing
  short8 afr[4][2];                 // A fragments of current (S,HA)
  short8 bf0[2][2], bf1[2][2];      // B fragments, half0 / half1 of current S

#define STAGE8(PTR, R0, KOFF, LP)                                            \
  {                                                                          \
    const short* g_ = (PTR) + (size_t)((R0) + sr) * 1280 + (KOFF) + sjs * 8; \
    gload_lds16(g_, (LP) + t8s);                                             \
    gload_lds16(g_ + 64 * 1280, (LP) + t8s + 4096);                          \
  }

#define READ_A(S, H)                                                         \
  {                                                                          \
    _Pragma("unroll") for (int mt = 0; mt < 4; mt++) {                       \
      int rp_ = (arow + mt * 16) * 64;                                       \
      afr[mt][0] = *(const short8*)&Al[S][H][rp_ + soff0];                   \
      afr[mt][1] = *(const short8*)&Al[S][H][rp_ + soff1];                   \
    }                                                                        \
  }
#define READ_B(DST, S, H)                                                    \
  {                                                                          \
    _Pragma("unroll") for (int nt = 0; nt < 2; nt++) {                       \
      int rp_ = (brow + nt * 16) * 64;                                       \
      DST[nt][0] = *(const short8*)&Bl[S][H][rp_ + soff0];                   \
      DST[nt][1] = *(const short8*)&Bl[S][H][rp_ + soff1];                   \
    }                                                                        \
  }
// one quadrant cluster (16 MFMA) with a counted lgkm wait before it
#define CLUST(QM, QN, BF, WAITI)                                             \
  {                                                                          \
    asm volatile("s_waitcnt lgkmcnt(" #WAITI ")" ::: "memory");              \
    __builtin_amdgcn_sched_barrier(0);                                       \
    _Pragma("unroll") for (int mt = 0; mt < 4; mt++)                         \
      _Pragma("unroll") for (int nt = 0; nt < 2; nt++) {                     \
        acc[QM][QN][mt][nt] = MFMA(afr[mt][0], BF[nt][0], acc[QM][QN][mt][nt]); \
        acc[QM][QN][mt][nt] = MFMA(afr[mt][1], BF[nt][1], acc[QM][QN][mt][nt]); \
      }                                                                      \
  }
#define BAR() __builtin_amdgcn_s_barrier()
#define VW4()                                                                \
  {                                                                          \
    asm volatile("s_waitcnt vmcnt(4)" ::: "memory");                         \
    __builtin_amdgcn_sched_barrier(0);                                       \
  }

  // prologue: tile0 (all 4 halves) + tile1 (A0,B0) = 12 loads/thread
  STAGE8(X,  m0,       0,  &Al[0][0][0]);
  STAGE8(X,  m0 + 128, 0,  &Al[0][1][0]);
  STAGE8(Wt, n0,       0,  &Bl[0][0][0]);
  STAGE8(Wt, n0 + 128, 0,  &Bl[0][1][0]);
  STAGE8(X,  m0,       64, &Al[1][0][0]);
  STAGE8(Wt, n0,       64, &Bl[1][0][0]);
  VW4();   // tile0's 8 loads landed
  BAR();

  for (int i = 0; i < 10; i++) {
    int k1 = (2 * i + 1) * 64;                       // <= 1216, always valid
    int k2 = (2 * i + 2) * 64; if (k2 >= K) k2 = 0;  // dummy (unread) on tail
    int k3 = (2 * i + 3) * 64; if (k3 >= K) k3 = 0;
    // ---- PhA (S=0): quadrants (0,0)+(0,1), 16 reads, 2 stage-pairs ----
    READ_A(0, 0); READ_B(bf0, 0, 0); READ_B(bf1, 0, 1);
    STAGE8(X,  m0 + 128, k1, &Al[1][1][0]);
    STAGE8(Wt, n0 + 128, k1, &Bl[1][1][0]);
    __builtin_amdgcn_s_setprio(1);
    CLUST(0, 0, bf0, 4);   // bf1's 4 reads land under this cluster
    CLUST(0, 1, bf1, 0);
    __builtin_amdgcn_s_setprio(0);
    BAR();
    // ---- PhB (S=0): quadrants (1,0)+(1,1), 8 reads ----
    READ_A(0, 1);
    STAGE8(X,  m0,       k2, &Al[0][0][0]);
    STAGE8(Wt, n0,       k2, &Bl[0][0][0]);
    __builtin_amdgcn_s_setprio(1);
    CLUST(1, 0, bf0, 0);
    CLUST(1, 1, bf1, 0);
    __builtin_amdgcn_s_setprio(0);
    VW4();                 // drains prevB + PhA stages -> slot1 ready
    BAR();
    // ---- PhA (S=1) ----
    READ_A(1, 0); READ_B(bf0, 1, 0); READ_B(bf1, 1, 1);
    STAGE8(X,  m0 + 128, k2, &Al[0][1][0]);
    STAGE8(Wt, n0 + 128, k2, &Bl[0][1][0]);
    __builtin_amdgcn_s_setprio(1);
    CLUST(0, 0, bf0, 4);
    CLUST(0, 1, bf1, 0);
    __builtin_amdgcn_s_setprio(0);
    BAR();
    // ---- PhB (S=1) ----
    READ_A(1, 1);
    STAGE8(X,  m0,       k3, &Al[1][0][0]);
    STAGE8(Wt, n0,       k3, &Bl[1][0][0]);
    __builtin_amdgcn_s_setprio(1);
    CLUST(1, 0, bf0, 0);
    CLUST(1, 1, bf1, 0);
    __builtin_amdgcn_s_setprio(0);
    VW4();                 // drains PhB(S=0) + PhA(S=1) stages -> slot0 ready
    BAR();
  }
  asm volatile("s_waitcnt vmcnt(0)" ::: "memory");   // drain dummy stages
  __builtin_amdgcn_sched_barrier(0);

  bool isb = probe_is_bf16(probe);
  float bv[2][2];
#pragma unroll
  for (int qn = 0; qn < 2; qn++)
#pragma unroll
    for (int nt = 0; nt < 2; nt++)
      bv[qn][nt] =
          load_scalar(bias, n0 + qn * 128 + (w & 3) * 32 + nt * 16 + l16, isb);
#pragma unroll
  for (int qm = 0; qm < 2; qm++)
#pragma unroll
    for (int mt = 0; mt < 4; mt++) {
      int mbase = m0 + qm * 128 + (w >> 2) * 64 + mt * 16 + quad * 4;
      int b = mbase >> 10, sbase = mbase & 1023;
#pragma unroll
      for (int qn = 0; qn < 2; qn++)
#pragma unroll
        for (int nt = 0; nt < 2; nt++) {
          int n = n0 + qn * 128 + (w & 3) * 32 + nt * 16 + l16;
          int which = n / 1280;
          int rmod = n - which * 1280;
          int h = rmod / 80;
          int d = rmod - h * 80;
          int bh = b * 16 + h;
          if (which == 2) {
            short4v vv;
#pragma unroll
            for (int reg = 0; reg < 4; reg++)
              vv[reg] = f2b(acc[qm][qn][mt][nt][reg] + bv[qn][nt]);
            *(short4v*)&Vt[((size_t)bh * 80 + d) * 1024 + sbase] = vv;
          } else {
            short* dst = (which == 0 ? Qw : Kw);
#pragma unroll
            for (int reg = 0; reg < 4; reg++)
              dst[((size_t)bh * 1024 + sbase + reg) * HDP + d] =
                  f2b(acc[qm][qn][mt][nt][reg] + bv[qn][nt]);
          }
        }
    }
#undef STAGE8
#undef READ_A
#undef READ_B
#undef CLUST
#undef BAR
#undef VW4
}

// ---------------------------------------------------------------- RoPE
// r10 (verified): vectorized; each thread owns chunk pair (p*8, 40+p*8).
__global__ __launch_bounds__(256) void rope_kernel(
    short* __restrict__ Qw, short* __restrict__ Kw,
    const void* __restrict__ cosb, const void* __restrict__ sinb,
    const unsigned* __restrict__ probe) {
  bool isb = probe_is_bf16(probe);
  int tg = blockIdx.x * 256 + threadIdx.x;   // 0..655359
  int row_all = tg / 5;                      // 0..131071
  int p = tg - row_all * 5;                  // 0..4
  int which = row_all >> 16;                 // 0 = Q, 1 = K
  int r = row_all & 65535;                   // bh*1024 + s
  int s = r & 1023;
  short* ptr = (which ? Kw : Qw) + (size_t)r * HDP;
  float scale = which ? 1.0f : SCALE_F;
  int d0 = p * 8, d1 = 40 + p * 8;
  short8 a = *(const short8*)&ptr[d0];
  short8 b = *(const short8*)&ptr[d1];
  float c0[8], s0[8], c1[8], s1[8];
  if (isb) {
    const short* cb = (const short*)cosb + s * 80;
    const short* sb = (const short*)sinb + s * 80;
    short8 vc0 = *(const short8*)&cb[d0];
    short8 vs0 = *(const short8*)&sb[d0];
    short8 vc1 = *(const short8*)&cb[d1];
    short8 vs1 = *(const short8*)&sb[d1];
#pragma unroll
    for (int j = 0; j < 8; j++) {
      c0[j] = bf2f(vc0[j]); s0[j] = bf2f(vs0[j]);
      c1[j] = bf2f(vc1[j]); s1[j] = bf2f(vs1[j]);
    }
  } else {
    const float* cb = (const float*)cosb + s * 80;
    const float* sb = (const float*)sinb + s * 80;
    float4 vc0a = *(const float4*)&cb[d0];
    float4 vc0b = *(const float4*)&cb[d0 + 4];
    float4 vs0a = *(const float4*)&sb[d0];
    float4 vs0b = *(const float4*)&sb[d0 + 4];
    float4 vc1a = *(const float4*)&cb[d1];
    float4 vc1b = *(const float4*)&cb[d1 + 4];
    float4 vs1a = *(const float4*)&sb[d1];
    float4 vs1b = *(const float4*)&sb[d1 + 4];
    c0[0] = vc0a.x; c0[1] = vc0a.y; c0[2] = vc0a.z; c0[3] = vc0a.w;
    c0[4] = vc0b.x; c0[5] = vc0b.y; c0[6] = vc0b.z; c0[7] = vc0b.w;
    s0[0] = vs0a.x; s0[1] = vs0a.y; s0[2] = vs0a.z; s0[3] = vs0a.w;
    s0[4] = vs0b.x; s0[5] = vs0b.y; s0[6] = vs0b.z; s0[7] = vs0b.w;
    c1[0] = vc1a.x; c1[1] = vc1a.y; c1[2] = vc1a.z; c1[3] = vc1a.w;
    c1[4] = vc1b.x; c1[5] = vc1b.y; c1[6] = vc1b.z; c1[7] = vc1b.w;
    s1[0] = vs1a.x; s1[1] = vs1a.y; s1[2] = vs1a.z; s1[3] = vs1a.w;
    s1[4] = vs1b.x; s1[5] = vs1b.y; s1[6] = vs1b.z; s1[7] = vs1b.w;
  }
  short8 o0, o1;
#pragma unroll
  for (int j = 0; j < 8; j++) {
    float av = bf2f(a[j]), bv = bf2f(b[j]);
    o0[j] = f2b((av * c0[j] - bv * s0[j]) * scale);
    o1[j] = f2b((bv * c1[j] + av * s1[j]) * scale);
  }
  *(short8*)&ptr[d0] = o0;
  *(short8*)&ptr[d1] = o1;
  if (p == 0) {
    short8 z = {};
    *(short8*)&ptr[80] = z;
    *(short8*)&ptr[88] = z;
  }
}

// ---------------------------------------------------------------- attention
// r17: 8 waves x 32 q-rows = 256 rows/block, grid 256 (= 1 block/CU, same
// 8 waves/CU as r16): K/V global fetch per bh halves (4 blocks share K/V
// instead of 8), staging cost per row halves (512-thread r5-verified
// staging), barrier count per row halves. Per-wave inner code byte-identical
// to the r16-verified 2-group form.
__global__ __launch_bounds__(512, 2) void attn_kernel(
    const short* __restrict__ Qw, const short* __restrict__ Kw,
    const short* __restrict__ Vt, short* __restrict__ out) {
  __shared__ short Klds[2][64 * 104];
  __shared__ short Vlds[2][80 * 72];
  int t = threadIdx.x;
  int w = t >> 6, lane = t & 63;
  int quad = lane >> 4, l16 = lane & 15;
  int bh = blockIdx.x & 63;        // XCD swizzle: same bh -> same XCD
  int qt = blockIdx.x >> 6;        // 0..3
  int q0 = qt * 256;
  const short* Kb = Kw + (size_t)bh * 1024 * HDP;
  const short* Vb = Vt + (size_t)bh * 80 * 1024;

  // Q fragments for both 16-row groups (rows q0 + w*32 + g*16 + l16)
  short8 aq0[3], aq1[3];
  {
    const short* qr0 = Qw + ((size_t)bh * 1024 + q0 + w * 32 + l16) * HDP;
    const short* qr1 = qr0 + 16 * HDP;
#pragma unroll
    for (int ks = 0; ks < 3; ks++) {
      aq0[ks] = *(const short8*)&qr0[ks * 32 + quad * 8];
      aq1[ks] = *(const short8*)&qr1[ks * 32 + quad * 8];
    }
  }

  // staging with 512 threads (r5-verified): K 768 slots; V 640 slots
  short8 kreg[2], vreg[2];
#define PREFETCH(c)                                                        \
  {                                                                        \
    {                                                                      \
      int row = t / 12, col = (t % 12) * 8;                                \
      kreg[0] = *(const short8*)&Kb[(size_t)((c) + row) * HDP + col];      \
    }                                                                      \
    if (t < 256) {                                                         \
      int idx = 512 + t;                                                   \
      int row = idx / 12, col = (idx % 12) * 8;                            \
      kreg[1] = *(const short8*)&Kb[(size_t)((c) + row) * HDP + col];      \
    }                                                                      \
    {                                                                      \
      int d = t >> 3, s0 = (t & 7) * 8;                                    \
      vreg[0] = *(const short8*)&Vb[(size_t)d * 1024 + (c) + s0];          \
    }                                                                      \
    if (t < 128) {                                                         \
      int idx = 512 + t;                                                   \
      int d = idx >> 3, s0 = (idx & 7) * 8;                                \
      vreg[1] = *(const short8*)&Vb[(size_t)d * 1024 + (c) + s0];          \
    }                                                                      \
  }
#define STORE_LDS(P)                                                       \
  {                                                                        \
    {                                                                      \
      int row = t / 12, col = (t % 12) * 8;                                \
      *(short8*)&Klds[P][row * 104 + col] = kreg[0];                       \
    }                                                                      \
    if (t < 256) {                                                         \
      int idx = 512 + t;                                                   \
      int row = idx / 12, col = (idx % 12) * 8;                            \
      *(short8*)&Klds[P][row * 104 + col] = kreg[1];                       \
    }                                                                      \
    {                                                                      \
      int d = t >> 3, s0 = (t & 7) * 8;                                    \
      *(short8*)&Vlds[P][d * 72 + s0] = vreg[0];                           \
    }                                                                      \
    if (t < 128) {                                                         \
      int idx = 512 + t;                                                   \
      int d = idx >> 3, s0 = (idx & 7) * 8;                                \
      *(short8*)&Vlds[P][d * 72 + s0] = vreg[1];                           \
    }                                                                      \
  }

  PREFETCH(0);
  STORE_LDS(0);
  __syncthreads();

  f32x4 ofr0[5] = {}, ofr1[5] = {};
  float lsum0 = 0.f, lsum1 = 0.f;

  int p = 0;
  for (int c = 0; c < 1024; c += 64, p ^= 1) {
    if (c + 64 < 1024) PREFETCH(c + 64);   // global loads fly under compute
    const short* Kl = &Klds[p][0];
    const short* Vl = &Vlds[p][0];
    // swapped QK^T, both q-groups share the K fragments (12 reads -> 24 MFMA)
    f32x4 sf0[4] = {}, sf1[4] = {};
#pragma unroll
    for (int nt = 0; nt < 4; nt++) {
      short8 bk0 = *(const short8*)&Kl[(nt * 16 + l16) * 104 + 0 * 32 + quad * 8];
      short8 bk1 = *(const short8*)&Kl[(nt * 16 + l16) * 104 + 1 * 32 + quad * 8];
      short8 bk2 = *(const short8*)&Kl[(nt * 16 + l16) * 104 + 2 * 32 + quad * 8];
      sf0[nt] = MFMA(bk0, aq0[0], sf0[nt]);
      sf1[nt] = MFMA(bk0, aq1[0], sf1[nt]);
      sf0[nt] = MFMA(bk1, aq0[1], sf0[nt]);
      sf1[nt] = MFMA(bk1, aq1[1], sf1[nt]);
      sf0[nt] = MFMA(bk2, aq0[2], sf0[nt]);
      sf1[nt] = MFMA(bk2, aq1[2], sf1[nt]);
    }
    // unsafe softmax in-register, both groups
    short4v bp0[4], bp1[4];
#pragma unroll
    for (int nt = 0; nt < 4; nt++) {
      float e0 = __expf(fminf(sf0[nt][0], 30.f));
      float e1 = __expf(fminf(sf0[nt][1], 30.f));
      float e2 = __expf(fminf(sf0[nt][2], 30.f));
      float e3 = __expf(fminf(sf0[nt][3], 30.f));
      lsum0 += (e0 + e1) + (e2 + e3);
      bp0[nt][0] = f2b(e0); bp0[nt][1] = f2b(e1);
      bp0[nt][2] = f2b(e2); bp0[nt][3] = f2b(e3);
      float f0 = __expf(fminf(sf1[nt][0], 30.f));
      float f1 = __expf(fminf(sf1[nt][1], 30.f));
      float f2 = __expf(fminf(sf1[nt][2], 30.f));
      float f3 = __expf(fminf(sf1[nt][3], 30.f));
      lsum1 += (f0 + f1) + (f2 + f3);
      bp1[nt][0] = f2b(f0); bp1[nt][1] = f2b(f1);
      bp1[nt][2] = f2b(f2); bp1[nt][3] = f2b(f3);
    }
    // PV: each V fragment read feeds both groups (20 reads -> 40 MFMA16)
#pragma unroll
    for (int cc = 0; cc < 4; cc++)
#pragma unroll
      for (int nt5 = 0; nt5 < 5; nt5++) {
        short4v va =
            *(const short4v*)&Vl[(nt5 * 16 + l16) * 72 + cc * 16 + quad * 4];
        ofr0[nt5] = MFMA16(va, bp0[cc], ofr0[nt5]);
        ofr1[nt5] = MFMA16(va, bp1[cc], ofr1[nt5]);
      }
    if (c + 64 < 1024) {
      STORE_LDS(p ^ 1);       // idle buffer; readers of it passed last barrier
      __syncthreads();        // publish + close this iter's reads of buf p
    }
  }
  // row sums (per group): partials live in the 4 lanes sharing l16
  lsum0 += __shfl_xor(lsum0, 16);
  lsum0 += __shfl_xor(lsum0, 32);
  lsum1 += __shfl_xor(lsum1, 16);
  lsum1 += __shfl_xor(lsum1, 32);
  float inv0 = 1.f / lsum0, inv1 = 1.f / lsum1;
  int b = bh >> 4, h = bh & 15;
  int s0r = q0 + w * 32 + l16;
  int s1r = s0r + 16;
#pragma unroll
  for (int nt5 = 0; nt5 < 5; nt5++) {
    short4v o0, o1;
#pragma unroll
    for (int j = 0; j < 4; j++) {
      o0[j] = f2b(ofr0[nt5][j] * inv0);
      o1[j] = f2b(ofr1[nt5][j] * inv1);
    }
    *(short4v*)&out[((size_t)(b * 1024 + s0r)) * 1280 + h * 80 + nt5 * 16 +
                    quad * 4] = o0;
    *(short4v*)&out[((size_t)(b * 1024 + s1r)) * 1280 + h * 80 + nt5 * 16 +
                    quad * 4] = o1;
  }
}

// ---------------------------------------------------------------- proj GEMM
__global__ __launch_bounds__(256) void gemm_proj_kernel(
    const short* __restrict__ A, const short* __restrict__ Wt,
    const void* __restrict__ bias, const unsigned* __restrict__ probe,
    float* __restrict__ out) {
  const int K = 1280;
  __shared__ short As[2][128 * 32];
  __shared__ short Bs[2][128 * 32];
  int t = threadIdx.x;
  int bm = blockIdx.x / 10;
  int bn = blockIdx.x % 10;
  int m0 = bm * 128, n0 = bn * 128;
  int w = t >> 6, lane = t & 63;
  int wm = w & 1, wn = w >> 1;
  int quad = lane >> 4, l16 = lane & 15;
  int row = t >> 2, ch = (t & 3) * 8, row2 = row + 64;
  int t8 = t * 8;
  const short* Ar  = A  + (size_t)(m0 + row)  * K + ch;
  const short* Ar2 = A  + (size_t)(m0 + row2) * K + ch;
  const short* Wr  = Wt + (size_t)(n0 + row)  * K + ch;
  const short* Wr2 = Wt + (size_t)(n0 + row2) * K + ch;
  f32x4 acc[4][4] = {};
  gload_lds16(Ar,  &As[0][t8]);
  gload_lds16(Ar2, &As[0][t8 + 2048]);
  gload_lds16(Wr,  &Bs[0][t8]);
  gload_lds16(Wr2, &Bs[0][t8 + 2048]);
  __syncthreads();
  int p = 0;
#define PROJ_COMPUTE(pp)                                                      \
  {                                                                           \
    short8 af[4], bfr[4];                                                     \
    _Pragma("unroll") for (int mt = 0; mt < 4; mt++)                          \
        af[mt] = *(const short8*)&As[pp][(wm * 64 + mt * 16 + l16) * 32 + quad * 8]; \
    _Pragma("unroll") for (int nt = 0; nt < 4; nt++)                          \
        bfr[nt] = *(const short8*)&Bs[pp][(wn * 64 + nt * 16 + l16) * 32 + quad * 8]; \
    _Pragma("unroll") for (int mt = 0; mt < 4; mt++)                          \
        _Pragma("unroll") for (int nt = 0; nt < 4; nt++)                      \
            acc[mt][nt] = MFMA(af[mt], bfr[nt], acc[mt][nt]);                 \
  }
  for (int k0 = 32; k0 < K; k0 += 32, p ^= 1) {
    gload_lds16(Ar + k0,  &As[p ^ 1][t8]);
    gload_lds16(Ar2 + k0, &As[p ^ 1][t8 + 2048]);
    gload_lds16(Wr + k0,  &Bs[p ^ 1][t8]);
    gload_lds16(Wr2 + k0, &Bs[p ^ 1][t8 + 2048]);
    PROJ_COMPUTE(p);
    __syncthreads();
  }
  PROJ_COMPUTE(p);
  bool isb = probe_is_bf16(probe);
  float bv[4];
#pragma unroll
  for (int nt = 0; nt < 4; nt++)
    bv[nt] = load_scalar(bias, n0 + wn * 64 + nt * 16 + l16, isb);
#pragma unroll
  for (int mt = 0; mt < 4; mt++) {
#pragma unroll
    for (int nt = 0; nt < 4; nt++) {
      int n = n0 + wn * 64 + nt * 16 + l16;
#pragma unroll
      for (int reg = 0; reg < 4; reg++) {
        int m = m0 + wm * 64 + mt * 16 + quad * 4 + reg;
        out[(size_t)m * 1280 + n] = acc[mt][nt][reg] + bv[nt];  // FP32 store
      }
    }
  }
}

extern "C" void kernel_launch(void* const* d_in, const int* in_sizes, int n_in,
                              void* d_out, int out_size, void* d_ws, size_t ws_size,
                              hipStream_t stream) {
  const void* x        = d_in[0];
  const void* rope_cos = d_in[1];
  const void* rope_sin = d_in[2];
  const void* Wqkv     = d_in[3];
  const void* bqkv     = d_in[4];
  const void* Wproj    = d_in[5];
  const void* bproj    = d_in[6];
  const unsigned* probe = (const unsigned*)rope_cos;
  char* ws = (char*)d_ws;
  short* Wt1 = (short*)(ws + 0);          // 1280*3840*2 = 9,830,400
  short* Wt2 = (short*)(ws + 9830400);    // 1280*1280*2 = 3,276,800
  short* Qw  = (short*)(ws + 13107200);   // 64*1024*96*2 = 12,582,912
  short* Kw  = (short*)(ws + 25690112);   // 12,582,912
  short* Vt  = (short*)(ws + 38273024);   // 64*1024*80*2 = 10,485,760
  short* Xb  = (short*)(ws + 48758784);   // 4096*1280*2 = 10,485,760
  short* At  = (short*)(ws + 48758784);   // aliases Xb (disjoint lifetimes)

  preproc_kernel<<<2560 + 6400, 256, 0, stream>>>(x, Xb, Wqkv, Wt1, Wproj, Wt2,
                                                  probe);
  gemm_qkv_kernel<<<240, 512, 0, stream>>>(Xb, Wt1, bqkv, probe, Qw, Kw, Vt);
  rope_kernel<<<2560, 256, 0, stream>>>(Qw, Kw, rope_cos, rope_sin, probe);
  attn_kernel<<<256, 512, 0, stream>>>(Qw, Kw, Vt, At);
  gemm_proj_kernel<<<32 * 10, 256, 0, stream>>>(At, Wt2, bproj, probe, (float*)d_out);
}